// Round 14
// baseline (418.791 us; speedup 1.0000x reference)
//
#include <hip/hip_runtime.h>
#include <hip/hip_bf16.h>
#include <math.h>

#define NTOK 8192
#define DM   1024
#define NE   16
#define HD   4096
#define CAP  640
#define NCHUNK 64   // (NTOK*2)/256

typedef float f32x4 __attribute__((ext_vector_type(4)));
typedef _Float16 f16x8 __attribute__((ext_vector_type(8)));
typedef _Float16 f16x4 __attribute__((ext_vector_type(4)));

__device__ __forceinline__ void gload16(const void* g, void* l) {
  __builtin_amdgcn_global_load_lds(
      (const __attribute__((address_space(1))) unsigned int*)g,
      (__attribute__((address_space(3))) unsigned int*)l, 16, 0, 0);
}

// fast GELU (tanh form)
__device__ __forceinline__ float gelu_fast(float v) {
  float v2 = v * v;
  float z2n = v * fmaf(-0.07135481627f, v2, -1.595769122f);
  float e = __expf(z2n);
  return v / (1.0f + e);
}

// ---------------- router: logits + softmax + col partials (one wave/token) ----------------
__global__ __launch_bounds__(256) void k_router(const float* __restrict__ x,
                                                const float* __restrict__ Wr,
                                                float* __restrict__ probs,
                                                float* __restrict__ pout) {
  int wave = threadIdx.x >> 6, lane = threadIdx.x & 63;
  int tok = blockIdx.x * 4 + wave;
  const float* xr = x + (size_t)tok * DM;
  float acc[NE];
#pragma unroll
  for (int e = 0; e < NE; ++e) acc[e] = 0.f;
  for (int d = lane; d < DM; d += 64) {
    float xv = xr[d];
    const float* w = Wr + (size_t)d * NE;
#pragma unroll
    for (int e = 0; e < NE; ++e) acc[e] = fmaf(xv, w[e], acc[e]);
  }
#pragma unroll
  for (int off = 32; off >= 1; off >>= 1) {
#pragma unroll
    for (int e = 0; e < NE; ++e) acc[e] += __shfl_xor(acc[e], off, 64);
  }
  float m = acc[0];
#pragma unroll
  for (int e = 1; e < NE; ++e) m = fmaxf(m, acc[e]);
  float s = 0.f;
#pragma unroll
  for (int e = 0; e < NE; ++e) { acc[e] = expf(acc[e] - m); s += acc[e]; }
  float inv = 1.0f / s;
#pragma unroll
  for (int e = 0; e < NE; ++e) acc[e] *= inv;
  if (lane < NE) probs[(size_t)tok * NE + lane] = acc[lane];
  __shared__ float wsum[4][NE];
  if (lane == 0) {
#pragma unroll
    for (int e = 0; e < NE; ++e) wsum[wave][e] = acc[e];
  }
  __syncthreads();
  if (threadIdx.x < NE)
    pout[blockIdx.x * NE + threadIdx.x] =
        wsum[0][threadIdx.x] + wsum[1][threadIdx.x] + wsum[2][threadIdx.x] + wsum[3][threadIdx.x];
}

// ------------- fused sinkhorn step -------------
__global__ __launch_bounds__(256) void k_sink(float* __restrict__ probs,
                                              const float* __restrict__ pin,
                                              float* __restrict__ pout) {
  __shared__ float csinv[NE];
  int tid = threadIdx.x;
  if (tid < NE) {
    float s = 0.f;
#pragma unroll
    for (int b = 0; b < 32; ++b) s += pin[b * NE + tid];
    csinv[tid] = 512.0f / s;
  }
  __syncthreads();
  int tok = blockIdx.x * 256 + tid;
  float* row = probs + (size_t)tok * NE;
  float p[NE]; float rs = 0.f;
#pragma unroll
  for (int e = 0; e < NE; ++e) { p[e] = row[e] * csinv[e]; rs += p[e]; }
  float rinv = 1.0f / rs;
#pragma unroll
  for (int e = 0; e < NE; ++e) { p[e] *= rinv; row[e] = p[e]; }
#pragma unroll
  for (int off = 32; off >= 1; off >>= 1) {
#pragma unroll
    for (int e = 0; e < NE; ++e) p[e] += __shfl_xor(p[e], off, 64);
  }
  __shared__ float wsum[4][NE];
  int lane = tid & 63, wave = tid >> 6;
  if (lane == 0) {
#pragma unroll
    for (int e = 0; e < NE; ++e) wsum[wave][e] = p[e];
  }
  __syncthreads();
  if (tid < NE)
    pout[blockIdx.x * NE + tid] =
        wsum[0][tid] + wsum[1][tid] + wsum[2][tid] + wsum[3][tid];
}

// ------------- final col-normalize + top-2 + renorm + fused per-chunk histogram -------------
__global__ __launch_bounds__(256) void k_sink3(const float* __restrict__ probs,
                                               const float* __restrict__ pin,
                                               int* __restrict__ eidx,
                                               float* __restrict__ ew,
                                               int* __restrict__ cnt) {
  __shared__ float csinv[NE];
  __shared__ int h0[NE], h1[NE];
  int tid = threadIdx.x;
  if (tid < NE) {
    float s = 0.f;
#pragma unroll
    for (int b = 0; b < 32; ++b) s += pin[b * NE + tid];
    csinv[tid] = 512.0f / s;
    h0[tid] = 0; h1[tid] = 0;
  }
  __syncthreads();
  int tok = blockIdx.x * 256 + tid;
  const float* row = probs + (size_t)tok * NE;
  float v0 = -1e30f, v1 = -1e30f; int e0 = 0, e1 = 0;
#pragma unroll
  for (int e = 0; e < NE; ++e) {
    float v = row[e] * csinv[e];
    if (v > v0) { v1 = v0; e1 = e0; v0 = v; e0 = e; }
    else if (v > v1) { v1 = v; e1 = e; }
  }
  float s = v0 + v1;
  eidx[tok * 2] = e0; eidx[tok * 2 + 1] = e1;
  ew[tok * 2] = v0 / s; ew[tok * 2 + 1] = v1 / s;
  int* hh = (tid < 128) ? h0 : h1;
  atomicAdd(&hh[e0], 1);
  atomicAdd(&hh[e1], 1);
  __syncthreads();
  if (tid < NE) cnt[(2 * blockIdx.x) * NE + tid] = h0[tid];
  else if (tid >= 32 && tid < 32 + NE) cnt[(2 * blockIdx.x + 1) * NE + (tid - 32)] = h1[tid - 32];
}

// ------------- per-expert exclusive prefix over chunks + aux loss -------------
__global__ __launch_bounds__(64) void k_prefix(const int* __restrict__ cnt,
                                               int* __restrict__ base,
                                               int* __restrict__ counts,
                                               float* __restrict__ aux) {
  __shared__ int tot[NE];
  int e = threadIdx.x;
  if (e < NE) {
    int run = 0;
    for (int c = 0; c < NCHUNK; ++c) {
      base[c * NE + e] = run;
      run += cnt[c * NE + e];
    }
    counts[e] = run;
    tot[e] = min(run, CAP);
  }
  __syncthreads();
  if (e == 0) {
    int s = 0;
#pragma unroll
    for (int i = 0; i < NE; ++i) s += tot[i];
    *aux = 0.01f * (float)s / (float)NTOK;
  }
}

__global__ __launch_bounds__(256) void k_assign(const int* __restrict__ eidx,
                                                const int* __restrict__ base,
                                                int* __restrict__ slot_tok,
                                                int* __restrict__ tok2slot) {
  __shared__ int wcnt[4][NE];
  __shared__ int cbase[NE];
  int tid = threadIdx.x, c = blockIdx.x, lane = tid & 63, wave = tid >> 6;
  int i = c * 256 + tid;
  int myE = eidx[i];
  if (tid < NE) cbase[tid] = base[c * NE + tid];
  int mypre = 0;
#pragma unroll
  for (int e = 0; e < NE; ++e) {
    unsigned long long m = __ballot(myE == e);
    if (myE == e) mypre = __popcll(m & ((1ull << lane) - 1ull));
    if (lane == 0) wcnt[wave][e] = __popcll(m);
  }
  __syncthreads();
  int pre = 0;
  for (int w = 0; w < wave; ++w) pre += wcnt[w][myE];
  int pos = cbase[myE] + pre + mypre;
  if (pos < CAP) {
    slot_tok[myE * CAP + pos] = i >> 1;
    tok2slot[i] = myE * CAP + pos;
  } else {
    tok2slot[i] = -1;
  }
}

// ------------- gather expert inputs to fp16 (zero-fill unused slots) -------------
__global__ __launch_bounds__(256) void k_gather(const float* __restrict__ x,
                                                const int* __restrict__ slot_tok,
                                                _Float16* __restrict__ xg) {
  int row = blockIdx.x;
  int tok = slot_tok[row];
  int t = threadIdx.x;
  f16x4 h;
  if (tok >= 0) {
    float4 v = *(const float4*)(x + (size_t)tok * DM + t * 4);
    h[0] = (_Float16)v.x; h[1] = (_Float16)v.y; h[2] = (_Float16)v.z; h[3] = (_Float16)v.w;
  } else {
    h[0] = (_Float16)0.f; h[1] = (_Float16)0.f; h[2] = (_Float16)0.f; h[3] = (_Float16)0.f;
  }
  *(f16x4*)(xg + (size_t)row * DM + t * 4) = h;
}

// ==================== fp16 MFMA GEMMs, async A-dbuf + counted vmcnt ====================

__device__ __forceinline__ void stage_tileA128(const _Float16* gbase, int ld, int k0,
                                               _Float16* lds, int w, int lane) {
#pragma unroll
  for (int i = 0; i < 4; ++i) {
    int ci = (w * 4 + i) * 64 + lane;
    int row = ci >> 3, c = ci & 7;
    int cs = c ^ (row & 7);
    gload16(gbase + (size_t)row * ld + k0 + cs * 8, lds + (w * 4 + i) * 512);
  }
}

// clamped variant (pad rows read row `al`)
__device__ __forceinline__ void stage_tileA128c(const _Float16* gbase, int ld, int k0,
                                                _Float16* lds, int w, int lane, int al) {
#pragma unroll
  for (int i = 0; i < 4; ++i) {
    int ci = (w * 4 + i) * 64 + lane;
    int row = ci >> 3, c = ci & 7;
    int cs = c ^ (row & 7);
    int rc = row < al ? row : al;
    gload16(gbase + (size_t)rc * ld + k0 + cs * 8, lds + (w * 4 + i) * 512);
  }
}

__device__ __forceinline__ void loadB8(const float* gb, int ld, int k0, int tid, float4* L) {
  int nq = tid & 31, kc = tid >> 5;
  const float* p = gb + (size_t)(k0 + kc * 8) * ld + nq * 4;
#pragma unroll
  for (int j = 0; j < 8; ++j) L[j] = *(const float4*)(p + (size_t)j * ld);
}

__device__ __forceinline__ void writeB(_Float16* Bs, int tid, const float4* L) {
  int nq = tid & 31, kc = tid >> 5;
#pragma unroll
  for (int i = 0; i < 4; ++i) {
    int n = nq * 4 + i;
    int pos = kc ^ ((n ^ (n >> 2)) & 7);
    f16x8 v;
#pragma unroll
    for (int j = 0; j < 8; ++j) {
      float f = (i == 0) ? L[j].x : (i == 1) ? L[j].y : (i == 2) ? L[j].z : L[j].w;
      v[j] = (_Float16)f;
    }
    *(f16x8*)(Bs + n * 64 + pos * 8) = v;
  }
}

// ---- GEMM1 v2: 256m x 128n per block, 2 m-tiles share one converted B tile ----
// LDS (dyn 80 KB): A[buf][tile] 4 x 16 KB | Bs 16 KB. Waves 0,1 -> tile a; 2,3 -> tile b.
// Per k-step: writeB || stageA(a,t+1)+stageA(b,t+1) |fence| loadB8(t+2-regs) -> lgkm(0) ->
// barrier -> MFMA 64/wave -> vmcnt(8) (16 in flight, 8 youngest are B -> drains all 8 A) -> barrier.
__global__ __launch_bounds__(256) void k_gemm1(const _Float16* __restrict__ xg,
                                               const float* __restrict__ W1,
                                               const float* __restrict__ b1,
                                               _Float16* __restrict__ hbuf) {
  extern __shared__ _Float16 smem[];
  _Float16* Bs = smem + 32768;
  int bid = blockIdx.x;
  int logical = (bid & 7) * 192 + (bid >> 3);     // 1536 = 8*192, bijective
  int mp = logical % 3;
  int nx = (logical / 3) % 32;
  int e  = logical / 96;
  int m0 = mp * 256, n0 = nx * 128;
  const _Float16* Aa = xg + ((size_t)e * CAP + m0) * DM;
  const _Float16* Ab2 = xg + ((size_t)e * CAP + m0 + 128) * DM;
  int alB = CAP - 1 - m0 - 128;                   // 511 / 255 / -1
  if (alB < 0) alB = 0;
  if (alB > 127) alB = 127;
  const float* Bb = W1 + (size_t)e * DM * HD + n0;   // ld = HD
  int tid = threadIdx.x, lane = tid & 63, w = tid >> 6;
  int wh = w & 1;                                  // row-half within the 128-tile
  int lr = lane & 15, kg = lane >> 4, lq = kg;

  f32x4 acc[4][8];
#pragma unroll
  for (int m = 0; m < 4; ++m)
#pragma unroll
    for (int n = 0; n < 8; ++n) acc[m][n] = (f32x4){0.f, 0.f, 0.f, 0.f};

  float4 L[8];
  // prologue
  stage_tileA128(Aa, DM, 0, smem, w, lane);
  stage_tileA128c(Ab2, DM, 0, smem + 8192, w, lane, alB);
  loadB8(Bb, HD, 0, tid, L);
  asm volatile("s_waitcnt vmcnt(0)" ::: "memory");
  __builtin_amdgcn_s_barrier();
  __builtin_amdgcn_sched_barrier(0);

  for (int t = 0; t < 16; ++t) {
    const _Float16* Ac = smem + ((t & 1) * 2 + (w >> 1)) * 8192;
    _Float16* AnA = smem + (((t + 1) & 1) * 2 + 0) * 8192;
    _Float16* AnB = smem + (((t + 1) & 1) * 2 + 1) * 8192;
    writeB(Bs, tid, L);
    if (t + 1 < 16) {
      stage_tileA128(Aa, DM, (t + 1) * 64, AnA, w, lane);
      stage_tileA128c(Ab2, DM, (t + 1) * 64, AnB, w, lane, alB);
      __builtin_amdgcn_sched_barrier(0);
      loadB8(Bb, HD, (t + 1) * 64, tid, L);
    }
    asm volatile("s_waitcnt lgkmcnt(0)" ::: "memory");
    __builtin_amdgcn_s_barrier();
    __builtin_amdgcn_sched_barrier(0);
#pragma unroll
    for (int ks = 0; ks < 2; ++ks) {
      f16x8 af[4], bf[8];
#pragma unroll
      for (int m = 0; m < 4; ++m) {
        int row = wh * 64 + m * 16 + lr;
        int cs = (ks * 4 + kg) ^ (row & 7);
        af[m] = *(const f16x8*)(Ac + row * 64 + cs * 8);
      }
#pragma unroll
      for (int n = 0; n < 8; ++n) {
        int row = n * 16 + lr;
        int cs = (ks * 4 + kg) ^ ((row ^ (row >> 2)) & 7);
        bf[n] = *(const f16x8*)(Bs + row * 64 + cs * 8);
      }
      __builtin_amdgcn_s_setprio(1);
#pragma unroll
      for (int m = 0; m < 4; ++m)
#pragma unroll
        for (int n = 0; n < 8; ++n)
          acc[m][n] = __builtin_amdgcn_mfma_f32_16x16x32_f16(af[m], bf[n], acc[m][n], 0, 0, 0);
      __builtin_amdgcn_s_setprio(0);
    }
    __builtin_amdgcn_sched_barrier(0);
    if (t + 1 < 16) { asm volatile("s_waitcnt vmcnt(8)" ::: "memory"); }
    else            { asm volatile("s_waitcnt vmcnt(0)" ::: "memory"); }
    __builtin_amdgcn_s_barrier();
    __builtin_amdgcn_sched_barrier(0);
  }

  // epilogue: bias + fast GELU -> fp16, bounce via LDS (256x128, 64 KB) for coalesced stores
  __syncthreads();
  _Float16* Cb = smem;
#pragma unroll
  for (int n = 0; n < 8; ++n) {
    int col = n * 16 + lr;
    float bias = b1[(size_t)e * HD + n0 + col];
#pragma unroll
    for (int m = 0; m < 4; ++m) {
#pragma unroll
      for (int r = 0; r < 4; ++r) {
        int row = w * 64 + m * 16 + lq * 4 + r;     // 0..255
        float v = gelu_fast(acc[m][n][r] + bias);
        Cb[row * 128 + (col ^ (((row >> 2) & 3) << 4))] = (_Float16)v;
      }
    }
  }
  __syncthreads();
  int rr = tid >> 4;
  int c8 = (tid & 15) * 8;
#pragma unroll
  for (int p = 0; p < 16; ++p) {
    int row = p * 16 + rr;
    if (m0 + row < CAP) {
      int colx = c8 ^ (((row >> 2) & 3) << 4);
      f16x8 v = *(const f16x8*)(Cb + row * 128 + colx);
      *(f16x8*)(hbuf + ((size_t)e * CAP + m0 + row) * HD + n0 + c8) = v;
    }
  }
}

#define MFMA_PHASE(Ac, Bs)                                                         \
  _Pragma("unroll")                                                                \
  for (int ks = 0; ks < 2; ++ks) {                                                 \
    f16x8 af[4], bf[4];                                                            \
    _Pragma("unroll")                                                              \
    for (int m = 0; m < 4; ++m) {                                                  \
      int row = wr * 64 + m * 16 + lr;                                             \
      int cs = (ks * 4 + kg) ^ (row & 7);                                          \
      af[m] = *(const f16x8*)((Ac) + row * 64 + cs * 8);                           \
    }                                                                              \
    _Pragma("unroll")                                                              \
    for (int n = 0; n < 4; ++n) {                                                  \
      int row = wc * 64 + n * 16 + lr;                                             \
      int cs = (ks * 4 + kg) ^ ((row ^ (row >> 2)) & 7);                           \
      bf[n] = *(const f16x8*)((Bs) + row * 64 + cs * 8);                           \
    }                                                                              \
    __builtin_amdgcn_s_setprio(1);                                                 \
    _Pragma("unroll")                                                              \
    for (int m = 0; m < 4; ++m)                                                    \
      _Pragma("unroll")                                                            \
      for (int n = 0; n < 4; ++n)                                                  \
        acc[m][n] = __builtin_amdgcn_mfma_f32_16x16x32_f16(af[m], bf[n], acc[m][n], 0, 0, 0); \
    __builtin_amdgcn_s_setprio(0);                                                 \
  }

#define ASYNC_K_LOOP(NT, AB, ALD, BB, BLD, KBASE)                                  \
  {                                                                                \
    stage_tileA128((AB), (ALD), (KBASE), As0, w, lane);                            \
    loadB8((BB), (BLD), (KBASE), tid, L);                                          \
    asm volatile("s_waitcnt vmcnt(0)" ::: "memory");                               \
    __builtin_amdgcn_s_barrier();                                                  \
    __builtin_amdgcn_sched_barrier(0);                                             \
    for (int t = 0; t < (NT); ++t) {                                               \
      const _Float16* Ac = (t & 1) ? As1 : As0;                                    \
      _Float16* An = (t & 1) ? As0 : As1;                                          \
      writeB(Bs, tid, L);                                                          \
      if (t + 1 < (NT)) {                                                          \
        stage_tileA128((AB), (ALD), (KBASE) + (t + 1) * 64, An, w, lane);          \
        loadB8((BB), (BLD), (KBASE) + (t + 1) * 64, tid, L);                       \
      }                                                                            \
      asm volatile("s_waitcnt lgkmcnt(0)" ::: "memory");                           \
      __builtin_amdgcn_s_barrier();                                                \
      __builtin_amdgcn_sched_barrier(0);                                           \
      MFMA_PHASE(Ac, Bs);                                                          \
      __builtin_amdgcn_sched_barrier(0);                                           \
      if (t + 1 < (NT)) { asm volatile("s_waitcnt vmcnt(8)" ::: "memory"); }       \
      else              { asm volatile("s_waitcnt vmcnt(0)" ::: "memory"); }       \
      __builtin_amdgcn_s_barrier();                                                \
      __builtin_amdgcn_sched_barrier(0);                                           \
    }                                                                              \
  }

// ---- GEMM2: Pks[e][slot] = h @ W2[kslice] (+b2 on ks==0), 128x128 tile, K-split 2, 1280 blocks ----
__global__ __launch_bounds__(256) void k_gemm2(const _Float16* __restrict__ hbuf,
                                               const float* __restrict__ W2,
                                               const float* __restrict__ b2,
                                               _Float16* __restrict__ P0,
                                               _Float16* __restrict__ P1) {
  __shared__ _Float16 smem[3 * 128 * 64];
  _Float16* As0 = smem;
  _Float16* As1 = smem + 8192;
  _Float16* Bs  = smem + 16384;
  int bid = blockIdx.x;
  int logical = (bid & 7) * 160 + (bid >> 3);
  int my = logical % 5;
  int nx = (logical / 5) % 8;
  int ks2 = (logical / 40) & 1;
  int e  = logical / 80;
  int m0 = my * 128, n0 = nx * 128, kbase = ks2 * 2048;
  const _Float16* Ab = hbuf + ((size_t)e * CAP + m0) * HD;
  const float*    Bb = W2 + (size_t)e * HD * DM + n0;     // ld = DM
  int tid = threadIdx.x, lane = tid & 63, w = tid >> 6;
  int wr = w >> 1, wc = w & 1;
  int lr = lane & 15, kg = lane >> 4;

  f32x4 acc[4][4];
#pragma unroll
  for (int m = 0; m < 4; ++m)
#pragma unroll
    for (int n = 0; n < 4; ++n) acc[m][n] = (f32x4){0.f, 0.f, 0.f, 0.f};

  float4 L[8];
  ASYNC_K_LOOP(32, Ab, HD, Bb, DM, kbase);

  // epilogue: (+bias on ks==0) -> fp16 partial via LDS bounce
  __syncthreads();
  _Float16* Cb = smem;
  _Float16* P = (ks2 == 0) ? P0 : P1;
  int lq = lane >> 4;
  float bias[4];
#pragma unroll
  for (int n = 0; n < 4; ++n)
    bias[n] = (ks2 == 0) ? b2[(size_t)e * DM + n0 + wc * 64 + n * 16 + lr] : 0.f;
#pragma unroll
  for (int m = 0; m < 4; ++m) {
#pragma unroll
    for (int n = 0; n < 4; ++n) {
#pragma unroll
      for (int r = 0; r < 4; ++r) {
        int row = wr * 64 + m * 16 + lq * 4 + r;
        int col = wc * 64 + n * 16 + lr;
        Cb[row * 128 + (col ^ (((row >> 2) & 3) << 4))] = (_Float16)(acc[m][n][r] + bias[n]);
      }
    }
  }
  __syncthreads();
  int rr = tid >> 4;
  int c8 = (tid & 15) * 8;
#pragma unroll
  for (int p = 0; p < 8; ++p) {
    int row = p * 16 + rr;
    int colx = c8 ^ (((row >> 2) & 3) << 4);
    f16x8 v = *(const f16x8*)(Cb + row * 128 + colx);
    *(f16x8*)(P + ((size_t)e * CAP + m0 + row) * DM + n0 + c8) = v;
  }
}

// ---- combine: y[t] = sum_k w_k * (P0[slot]+P1[slot]) ----
__global__ __launch_bounds__(256) void k_combine(const _Float16* __restrict__ P0,
                                                 const _Float16* __restrict__ P1,
                                                 const int* __restrict__ tok2slot,
                                                 const float* __restrict__ ew,
                                                 float* __restrict__ y) {
  int t = blockIdx.x;
  int d = threadIdx.x * 4;
  int i0 = tok2slot[t * 2], i1 = tok2slot[t * 2 + 1];
  float w0 = ew[t * 2], w1 = ew[t * 2 + 1];
  float a0 = 0.f, a1 = 0.f, a2 = 0.f, a3 = 0.f;
  if (i0 >= 0) {
    f16x4 oa = *(const f16x4*)(P0 + (size_t)i0 * DM + d);
    f16x4 ob = *(const f16x4*)(P1 + (size_t)i0 * DM + d);
    a0 += w0 * ((float)oa[0] + (float)ob[0]); a1 += w0 * ((float)oa[1] + (float)ob[1]);
    a2 += w0 * ((float)oa[2] + (float)ob[2]); a3 += w0 * ((float)oa[3] + (float)ob[3]);
  }
  if (i1 >= 0) {
    f16x4 oa = *(const f16x4*)(P0 + (size_t)i1 * DM + d);
    f16x4 ob = *(const f16x4*)(P1 + (size_t)i1 * DM + d);
    a0 += w1 * ((float)oa[0] + (float)ob[0]); a1 += w1 * ((float)oa[1] + (float)ob[1]);
    a2 += w1 * ((float)oa[2] + (float)ob[2]); a3 += w1 * ((float)oa[3] + (float)ob[3]);
  }
  float4 out = make_float4(a0, a1, a2, a3);
  *(float4*)(y + (size_t)t * DM + d) = out;
}

extern "C" void kernel_launch(void* const* d_in, const int* in_sizes, int n_in,
                              void* d_out, int out_size, void* d_ws, size_t ws_size,
                              hipStream_t stream) {
  const float* x  = (const float*)d_in[0];
  const float* Wr = (const float*)d_in[1];
  const float* W1 = (const float*)d_in[2];
  const float* b1 = (const float*)d_in[3];
  const float* W2 = (const float*)d_in[4];
  const float* b2 = (const float*)d_in[5];
  float* y = (float*)d_out;
  float* aux = y + (size_t)out_size - 1;

  char* ws = (char*)d_ws;
  float* probs    = (float*)ws; ws += (size_t)NTOK * NE * 4;   // 512 KB
  float* C0       = (float*)ws; ws += 32 * NE * 4;
  float* C1       = (float*)ws; ws += 32 * NE * 4;
  int*   eidx     = (int*)ws;   ws += NTOK * 2 * 4;
  float* ew       = (float*)ws; ws += NTOK * 2 * 4;
  int*   slot_tok = (int*)ws;   ws += NE * CAP * 4;
  int*   tok2slot = (int*)ws;   ws += NTOK * 2 * 4;
  int*   counts   = (int*)ws;   ws += 256;
  int*   cnt      = (int*)ws;   ws += NCHUNK * NE * 4;
  int*   cbase    = (int*)ws;   ws += NCHUNK * NE * 4;
  _Float16* xg    = (_Float16*)ws; ws += (size_t)NE * CAP * DM * 2;   // 20 MB
  _Float16* hbuf  = (_Float16*)ws; ws += (size_t)NE * CAP * HD * 2;   // 80 MB
  _Float16* P1b   = (_Float16*)ws; ws += (size_t)NE * CAP * DM * 2;   // 20 MB
  _Float16* P0b   = xg;   // xg dead after k_gemm1

  hipFuncSetAttribute((const void*)k_gemm1, hipFuncAttributeMaxDynamicSharedMemorySize, 81920);

  hipMemsetAsync(slot_tok, 0xFF, (size_t)NE * CAP * 4, stream);

  k_router<<<NTOK / 4, 256, 0, stream>>>(x, Wr, probs, C0);
  k_sink<<<32, 256, 0, stream>>>(probs, C0, C1);
  k_sink<<<32, 256, 0, stream>>>(probs, C1, C0);
  k_sink3<<<32, 256, 0, stream>>>(probs, C0, eidx, ew, cnt);
  k_prefix<<<1, 64, 0, stream>>>(cnt, cbase, counts, aux);
  k_assign<<<NCHUNK, 256, 0, stream>>>(eidx, cbase, slot_tok, tok2slot);
  k_gather<<<NE * CAP, 256, 0, stream>>>(x, slot_tok, xg);

  k_gemm1<<<1536, 256, 81920, stream>>>(xg, W1, b1, hbuf);
  k_gemm2<<<1280, 256, 0, stream>>>(hbuf, W2, b2, P0b, P1b);

  k_combine<<<NTOK, 256, 0, stream>>>(P0b, P1b, tok2slot, ew, y);
}

// Round 15
// 383.145 us; speedup vs baseline: 1.0930x; 1.0930x over previous
//
#include <hip/hip_runtime.h>
#include <hip/hip_bf16.h>
#include <math.h>

#define NTOK 8192
#define DM   1024
#define NE   16
#define HD   4096
#define CAP  640
#define NCHUNK 64   // (NTOK*2)/256

typedef float f32x4 __attribute__((ext_vector_type(4)));
typedef _Float16 f16x8 __attribute__((ext_vector_type(8)));
typedef _Float16 f16x4 __attribute__((ext_vector_type(4)));

__device__ __forceinline__ void gload16(const void* g, void* l) {
  __builtin_amdgcn_global_load_lds(
      (const __attribute__((address_space(1))) unsigned int*)g,
      (__attribute__((address_space(3))) unsigned int*)l, 16, 0, 0);
}

// fast GELU (tanh form)
__device__ __forceinline__ float gelu_fast(float v) {
  float v2 = v * v;
  float z2n = v * fmaf(-0.07135481627f, v2, -1.595769122f);
  float e = __expf(z2n);
  return v / (1.0f + e);
}

// ---------------- router: logits + softmax + col partials (one wave/token) ----------------
__global__ __launch_bounds__(256) void k_router(const float* __restrict__ x,
                                                const float* __restrict__ Wr,
                                                float* __restrict__ probs,
                                                float* __restrict__ pout) {
  int wave = threadIdx.x >> 6, lane = threadIdx.x & 63;
  int tok = blockIdx.x * 4 + wave;
  const float* xr = x + (size_t)tok * DM;
  float acc[NE];
#pragma unroll
  for (int e = 0; e < NE; ++e) acc[e] = 0.f;
  for (int d = lane; d < DM; d += 64) {
    float xv = xr[d];
    const float* w = Wr + (size_t)d * NE;
#pragma unroll
    for (int e = 0; e < NE; ++e) acc[e] = fmaf(xv, w[e], acc[e]);
  }
#pragma unroll
  for (int off = 32; off >= 1; off >>= 1) {
#pragma unroll
    for (int e = 0; e < NE; ++e) acc[e] += __shfl_xor(acc[e], off, 64);
  }
  float m = acc[0];
#pragma unroll
  for (int e = 1; e < NE; ++e) m = fmaxf(m, acc[e]);
  float s = 0.f;
#pragma unroll
  for (int e = 0; e < NE; ++e) { acc[e] = expf(acc[e] - m); s += acc[e]; }
  float inv = 1.0f / s;
#pragma unroll
  for (int e = 0; e < NE; ++e) acc[e] *= inv;
  if (lane < NE) probs[(size_t)tok * NE + lane] = acc[lane];
  __shared__ float wsum[4][NE];
  if (lane == 0) {
#pragma unroll
    for (int e = 0; e < NE; ++e) wsum[wave][e] = acc[e];
  }
  __syncthreads();
  if (threadIdx.x < NE)
    pout[blockIdx.x * NE + threadIdx.x] =
        wsum[0][threadIdx.x] + wsum[1][threadIdx.x] + wsum[2][threadIdx.x] + wsum[3][threadIdx.x];
}

// ------------- fused sinkhorn step -------------
__global__ __launch_bounds__(256) void k_sink(float* __restrict__ probs,
                                              const float* __restrict__ pin,
                                              float* __restrict__ pout) {
  __shared__ float csinv[NE];
  int tid = threadIdx.x;
  if (tid < NE) {
    float s = 0.f;
#pragma unroll
    for (int b = 0; b < 32; ++b) s += pin[b * NE + tid];
    csinv[tid] = 512.0f / s;
  }
  __syncthreads();
  int tok = blockIdx.x * 256 + tid;
  float* row = probs + (size_t)tok * NE;
  float p[NE]; float rs = 0.f;
#pragma unroll
  for (int e = 0; e < NE; ++e) { p[e] = row[e] * csinv[e]; rs += p[e]; }
  float rinv = 1.0f / rs;
#pragma unroll
  for (int e = 0; e < NE; ++e) { p[e] *= rinv; row[e] = p[e]; }
#pragma unroll
  for (int off = 32; off >= 1; off >>= 1) {
#pragma unroll
    for (int e = 0; e < NE; ++e) p[e] += __shfl_xor(p[e], off, 64);
  }
  __shared__ float wsum[4][NE];
  int lane = tid & 63, wave = tid >> 6;
  if (lane == 0) {
#pragma unroll
    for (int e = 0; e < NE; ++e) wsum[wave][e] = p[e];
  }
  __syncthreads();
  if (tid < NE)
    pout[blockIdx.x * NE + tid] =
        wsum[0][tid] + wsum[1][tid] + wsum[2][tid] + wsum[3][tid];
}

// ------------- final col-normalize + top-2 + renorm + fused per-chunk histogram -------------
// Block b handles tokens b*256..b*256+255 = dispatch entries 512b..512b+511 = chunks 2b, 2b+1.
__global__ __launch_bounds__(256) void k_sink3(const float* __restrict__ probs,
                                               const float* __restrict__ pin,
                                               int* __restrict__ eidx,
                                               float* __restrict__ ew,
                                               int* __restrict__ cnt) {
  __shared__ float csinv[NE];
  __shared__ int h0[NE], h1[NE];
  int tid = threadIdx.x;
  if (tid < NE) {
    float s = 0.f;
#pragma unroll
    for (int b = 0; b < 32; ++b) s += pin[b * NE + tid];
    csinv[tid] = 512.0f / s;
    h0[tid] = 0; h1[tid] = 0;
  }
  __syncthreads();
  int tok = blockIdx.x * 256 + tid;
  const float* row = probs + (size_t)tok * NE;
  float v0 = -1e30f, v1 = -1e30f; int e0 = 0, e1 = 0;
#pragma unroll
  for (int e = 0; e < NE; ++e) {
    float v = row[e] * csinv[e];
    if (v > v0) { v1 = v0; e1 = e0; v0 = v; e0 = e; }
    else if (v > v1) { v1 = v; e1 = e; }
  }
  float s = v0 + v1;
  eidx[tok * 2] = e0; eidx[tok * 2 + 1] = e1;
  ew[tok * 2] = v0 / s; ew[tok * 2 + 1] = v1 / s;
  // entries 2*tok, 2*tok+1 belong to chunk 2b (tid<128) or 2b+1 (tid>=128)
  int* hh = (tid < 128) ? h0 : h1;
  atomicAdd(&hh[e0], 1);
  atomicAdd(&hh[e1], 1);
  __syncthreads();
  if (tid < NE) cnt[(2 * blockIdx.x) * NE + tid] = h0[tid];
  else if (tid >= 32 && tid < 32 + NE) cnt[(2 * blockIdx.x + 1) * NE + (tid - 32)] = h1[tid - 32];
}

// ------------- per-expert exclusive prefix over chunks + aux loss -------------
__global__ __launch_bounds__(64) void k_prefix(const int* __restrict__ cnt,
                                               int* __restrict__ base,
                                               int* __restrict__ counts,
                                               float* __restrict__ aux) {
  __shared__ int tot[NE];
  int e = threadIdx.x;
  if (e < NE) {
    int run = 0;
    for (int c = 0; c < NCHUNK; ++c) {
      base[c * NE + e] = run;
      run += cnt[c * NE + e];
    }
    counts[e] = run;
    tot[e] = min(run, CAP);
  }
  __syncthreads();
  if (e == 0) {
    int s = 0;
#pragma unroll
    for (int i = 0; i < NE; ++i) s += tot[i];
    *aux = 0.01f * (float)s / (float)NTOK;
  }
}

__global__ __launch_bounds__(256) void k_assign(const int* __restrict__ eidx,
                                                const int* __restrict__ base,
                                                int* __restrict__ slot_tok,
                                                int* __restrict__ tok2slot) {
  __shared__ int wcnt[4][NE];
  __shared__ int cbase[NE];
  int tid = threadIdx.x, c = blockIdx.x, lane = tid & 63, wave = tid >> 6;
  int i = c * 256 + tid;
  int myE = eidx[i];
  if (tid < NE) cbase[tid] = base[c * NE + tid];
  int mypre = 0;
#pragma unroll
  for (int e = 0; e < NE; ++e) {
    unsigned long long m = __ballot(myE == e);
    if (myE == e) mypre = __popcll(m & ((1ull << lane) - 1ull));
    if (lane == 0) wcnt[wave][e] = __popcll(m);
  }
  __syncthreads();
  int pre = 0;
  for (int w = 0; w < wave; ++w) pre += wcnt[w][myE];
  int pos = cbase[myE] + pre + mypre;
  if (pos < CAP) {
    slot_tok[myE * CAP + pos] = i >> 1;
    tok2slot[i] = myE * CAP + pos;
  } else {
    tok2slot[i] = -1;
  }
}

// ------------- gather expert inputs to fp16 (zero-fill unused slots) -------------
__global__ __launch_bounds__(256) void k_gather(const float* __restrict__ x,
                                                const int* __restrict__ slot_tok,
                                                _Float16* __restrict__ xg) {
  int row = blockIdx.x;
  int tok = slot_tok[row];
  int t = threadIdx.x;
  f16x4 h;
  if (tok >= 0) {
    float4 v = *(const float4*)(x + (size_t)tok * DM + t * 4);
    h[0] = (_Float16)v.x; h[1] = (_Float16)v.y; h[2] = (_Float16)v.z; h[3] = (_Float16)v.w;
  } else {
    h[0] = (_Float16)0.f; h[1] = (_Float16)0.f; h[2] = (_Float16)0.f; h[3] = (_Float16)0.f;
  }
  *(f16x4*)(xg + (size_t)row * DM + t * 4) = h;
}

// ==================== fp16 MFMA GEMMs, async A-dbuf + counted vmcnt (r9-proven) ====================
// A-LDS: double-buffered [128][64k] fp16 (16 KB each), 16B chunks XOR-swizzled (c ^= row&7),
//        filled by global_load_lds (pre-swizzled global source, linear LDS dest).
// B-LDS: [128n][64k] fp16, chunk pos = kc ^ ((n^(n>>2))&7), reg-staged from fp32 W (fused
//        transpose+convert). B prefetch (8 float4) issued one k-step early.
// Loop: raw s_barrier + counted vmcnt(8) at step end (A(t+1)'s 4 gload16 drained, 8 B-loads
//       stay in flight) — A staging latency hides under the MFMA phase.

__device__ __forceinline__ void stage_tileA128(const _Float16* gbase, int ld, int k0,
                                               _Float16* lds, int w, int lane) {
#pragma unroll
  for (int i = 0; i < 4; ++i) {
    int ci = (w * 4 + i) * 64 + lane;
    int row = ci >> 3, c = ci & 7;
    int cs = c ^ (row & 7);
    gload16(gbase + (size_t)row * ld + k0 + cs * 8, lds + (w * 4 + i) * 512);
  }
}

__device__ __forceinline__ void loadB8(const float* gb, int ld, int k0, int tid, float4* L) {
  int nq = tid & 31, kc = tid >> 5;
  const float* p = gb + (size_t)(k0 + kc * 8) * ld + nq * 4;
#pragma unroll
  for (int j = 0; j < 8; ++j) L[j] = *(const float4*)(p + (size_t)j * ld);
}

__device__ __forceinline__ void writeB(_Float16* Bs, int tid, const float4* L) {
  int nq = tid & 31, kc = tid >> 5;
#pragma unroll
  for (int i = 0; i < 4; ++i) {
    int n = nq * 4 + i;
    int pos = kc ^ ((n ^ (n >> 2)) & 7);
    f16x8 v;
#pragma unroll
    for (int j = 0; j < 8; ++j) {
      float f = (i == 0) ? L[j].x : (i == 1) ? L[j].y : (i == 2) ? L[j].z : L[j].w;
      v[j] = (_Float16)f;
    }
    *(f16x8*)(Bs + n * 64 + pos * 8) = v;
  }
}

#define MFMA_PHASE(Ac, Bs)                                                         \
  _Pragma("unroll")                                                                \
  for (int ks = 0; ks < 2; ++ks) {                                                 \
    f16x8 af[4], bf[4];                                                            \
    _Pragma("unroll")                                                              \
    for (int m = 0; m < 4; ++m) {                                                  \
      int row = wr * 64 + m * 16 + lr;                                             \
      int cs = (ks * 4 + kg) ^ (row & 7);                                          \
      af[m] = *(const f16x8*)((Ac) + row * 64 + cs * 8);                           \
    }                                                                              \
    _Pragma("unroll")                                                              \
    for (int n = 0; n < 4; ++n) {                                                  \
      int row = wc * 64 + n * 16 + lr;                                             \
      int cs = (ks * 4 + kg) ^ ((row ^ (row >> 2)) & 7);                           \
      bf[n] = *(const f16x8*)((Bs) + row * 64 + cs * 8);                           \
    }                                                                              \
    __builtin_amdgcn_s_setprio(1);                                                 \
    _Pragma("unroll")                                                              \
    for (int m = 0; m < 4; ++m)                                                    \
      _Pragma("unroll")                                                            \
      for (int n = 0; n < 4; ++n)                                                  \
        acc[m][n] = __builtin_amdgcn_mfma_f32_16x16x32_f16(af[m], bf[n], acc[m][n], 0, 0, 0); \
    __builtin_amdgcn_s_setprio(0);                                                 \
  }

#define ASYNC_K_LOOP(NT, AB, ALD, BB, BLD, KBASE)                                  \
  {                                                                                \
    stage_tileA128((AB), (ALD), (KBASE), As0, w, lane);                            \
    loadB8((BB), (BLD), (KBASE), tid, L);                                          \
    asm volatile("s_waitcnt vmcnt(0)" ::: "memory");                               \
    __builtin_amdgcn_s_barrier();                                                  \
    __builtin_amdgcn_sched_barrier(0);                                             \
    for (int t = 0; t < (NT); ++t) {                                               \
      const _Float16* Ac = (t & 1) ? As1 : As0;                                    \
      _Float16* An = (t & 1) ? As0 : As1;                                          \
      writeB(Bs, tid, L);                                                          \
      if (t + 1 < (NT)) {                                                          \
        stage_tileA128((AB), (ALD), (KBASE) + (t + 1) * 64, An, w, lane);          \
        loadB8((BB), (BLD), (KBASE) + (t + 1) * 64, tid, L);                       \
      }                                                                            \
      asm volatile("s_waitcnt lgkmcnt(0)" ::: "memory");                           \
      __builtin_amdgcn_s_barrier();                                                \
      __builtin_amdgcn_sched_barrier(0);                                           \
      MFMA_PHASE(Ac, Bs);                                                          \
      __builtin_amdgcn_sched_barrier(0);                                           \
      if (t + 1 < (NT)) { asm volatile("s_waitcnt vmcnt(8)" ::: "memory"); }       \
      else              { asm volatile("s_waitcnt vmcnt(0)" ::: "memory"); }       \
      __builtin_amdgcn_s_barrier();                                                \
      __builtin_amdgcn_sched_barrier(0);                                           \
    }                                                                              \
  }

// ---- GEMM1: h = gelu(xg @ W1 + b1), 128x128 tile, 2560 blocks ----
__global__ __launch_bounds__(256) void k_gemm1(const _Float16* __restrict__ xg,
                                               const float* __restrict__ W1,
                                               const float* __restrict__ b1,
                                               _Float16* __restrict__ hbuf) {
  __shared__ _Float16 smem[3 * 128 * 64];     // As0 | As1 | Bs ; first 32 KB reused as bounce
  _Float16* As0 = smem;
  _Float16* As1 = smem + 8192;
  _Float16* Bs  = smem + 16384;
  int bid = blockIdx.x;
  int logical = (bid & 7) * 320 + (bid >> 3);
  int my = logical % 5;
  int nx = (logical / 5) % 32;
  int e  = logical / 160;
  int m0 = my * 128, n0 = nx * 128;
  const _Float16* Ab = xg + ((size_t)e * CAP + m0) * DM;
  const float*    Bb = W1 + (size_t)e * DM * HD + n0;     // ld = HD
  int tid = threadIdx.x, lane = tid & 63, w = tid >> 6;
  int wr = w >> 1, wc = w & 1;
  int lr = lane & 15, kg = lane >> 4;

  f32x4 acc[4][4];
#pragma unroll
  for (int m = 0; m < 4; ++m)
#pragma unroll
    for (int n = 0; n < 4; ++n) acc[m][n] = (f32x4){0.f, 0.f, 0.f, 0.f};

  float4 L[8];
  ASYNC_K_LOOP(16, Ab, DM, Bb, HD, 0);

  // epilogue: bias + fast GELU -> fp16, bounce via LDS for coalesced stores
  __syncthreads();
  _Float16* Cb = smem;
  int lq = lane >> 4;
#pragma unroll
  for (int n = 0; n < 4; ++n) {
    int col = wc * 64 + n * 16 + lr;
    float bias = b1[(size_t)e * HD + n0 + col];
#pragma unroll
    for (int m = 0; m < 4; ++m) {
#pragma unroll
      for (int r = 0; r < 4; ++r) {
        int row = wr * 64 + m * 16 + lq * 4 + r;
        float v = gelu_fast(acc[m][n][r] + bias);
        Cb[row * 128 + (col ^ (((row >> 2) & 3) << 4))] = (_Float16)v;
      }
    }
  }
  __syncthreads();
  int rr = tid >> 4;
  int c8 = (tid & 15) * 8;
#pragma unroll
  for (int p = 0; p < 8; ++p) {
    int row = p * 16 + rr;
    int colx = c8 ^ (((row >> 2) & 3) << 4);
    f16x8 v = *(const f16x8*)(Cb + row * 128 + colx);
    *(f16x8*)(hbuf + ((size_t)e * CAP + m0 + row) * HD + n0 + c8) = v;
  }
}

// ---- GEMM2: Pks[e][slot] = h @ W2[kslice] (+b2 on ks==0), 128x128 tile, K-split 2, 1280 blocks ----
__global__ __launch_bounds__(256) void k_gemm2(const _Float16* __restrict__ hbuf,
                                               const float* __restrict__ W2,
                                               const float* __restrict__ b2,
                                               _Float16* __restrict__ P0,
                                               _Float16* __restrict__ P1) {
  __shared__ _Float16 smem[3 * 128 * 64];
  _Float16* As0 = smem;
  _Float16* As1 = smem + 8192;
  _Float16* Bs  = smem + 16384;
  int bid = blockIdx.x;
  int logical = (bid & 7) * 160 + (bid >> 3);
  int my = logical % 5;
  int nx = (logical / 5) % 8;
  int ks2 = (logical / 40) & 1;
  int e  = logical / 80;
  int m0 = my * 128, n0 = nx * 128, kbase = ks2 * 2048;
  const _Float16* Ab = hbuf + ((size_t)e * CAP + m0) * HD;
  const float*    Bb = W2 + (size_t)e * HD * DM + n0;     // ld = DM
  int tid = threadIdx.x, lane = tid & 63, w = tid >> 6;
  int wr = w >> 1, wc = w & 1;
  int lr = lane & 15, kg = lane >> 4;

  f32x4 acc[4][4];
#pragma unroll
  for (int m = 0; m < 4; ++m)
#pragma unroll
    for (int n = 0; n < 4; ++n) acc[m][n] = (f32x4){0.f, 0.f, 0.f, 0.f};

  float4 L[8];
  ASYNC_K_LOOP(32, Ab, HD, Bb, DM, kbase);

  // epilogue: (+bias on ks==0) -> fp16 partial via LDS bounce
  __syncthreads();
  _Float16* Cb = smem;
  _Float16* P = (ks2 == 0) ? P0 : P1;
  int lq = lane >> 4;
  float bias[4];
#pragma unroll
  for (int n = 0; n < 4; ++n)
    bias[n] = (ks2 == 0) ? b2[(size_t)e * DM + n0 + wc * 64 + n * 16 + lr] : 0.f;
#pragma unroll
  for (int m = 0; m < 4; ++m) {
#pragma unroll
    for (int n = 0; n < 4; ++n) {
#pragma unroll
      for (int r = 0; r < 4; ++r) {
        int row = wr * 64 + m * 16 + lq * 4 + r;
        int col = wc * 64 + n * 16 + lr;
        Cb[row * 128 + (col ^ (((row >> 2) & 3) << 4))] = (_Float16)(acc[m][n][r] + bias[n]);
      }
    }
  }
  __syncthreads();
  int rr = tid >> 4;
  int c8 = (tid & 15) * 8;
#pragma unroll
  for (int p = 0; p < 8; ++p) {
    int row = p * 16 + rr;
    int colx = c8 ^ (((row >> 2) & 3) << 4);
    f16x8 v = *(const f16x8*)(Cb + row * 128 + colx);
    *(f16x8*)(P + ((size_t)e * CAP + m0 + row) * DM + n0 + c8) = v;
  }
}

// ---- combine: y[t] = sum_k w_k * (P0[slot]+P1[slot]) ----
__global__ __launch_bounds__(256) void k_combine(const _Float16* __restrict__ P0,
                                                 const _Float16* __restrict__ P1,
                                                 const int* __restrict__ tok2slot,
                                                 const float* __restrict__ ew,
                                                 float* __restrict__ y) {
  int t = blockIdx.x;
  int d = threadIdx.x * 4;
  int i0 = tok2slot[t * 2], i1 = tok2slot[t * 2 + 1];
  float w0 = ew[t * 2], w1 = ew[t * 2 + 1];
  float a0 = 0.f, a1 = 0.f, a2 = 0.f, a3 = 0.f;
  if (i0 >= 0) {
    f16x4 oa = *(const f16x4*)(P0 + (size_t)i0 * DM + d);
    f16x4 ob = *(const f16x4*)(P1 + (size_t)i0 * DM + d);
    a0 += w0 * ((float)oa[0] + (float)ob[0]); a1 += w0 * ((float)oa[1] + (float)ob[1]);
    a2 += w0 * ((float)oa[2] + (float)ob[2]); a3 += w0 * ((float)oa[3] + (float)ob[3]);
  }
  if (i1 >= 0) {
    f16x4 oa = *(const f16x4*)(P0 + (size_t)i1 * DM + d);
    f16x4 ob = *(const f16x4*)(P1 + (size_t)i1 * DM + d);
    a0 += w1 * ((float)oa[0] + (float)ob[0]); a1 += w1 * ((float)oa[1] + (float)ob[1]);
    a2 += w1 * ((float)oa[2] + (float)ob[2]); a3 += w1 * ((float)oa[3] + (float)ob[3]);
  }
  float4 out = make_float4(a0, a1, a2, a3);
  *(float4*)(y + (size_t)t * DM + d) = out;
}

extern "C" void kernel_launch(void* const* d_in, const int* in_sizes, int n_in,
                              void* d_out, int out_size, void* d_ws, size_t ws_size,
                              hipStream_t stream) {
  const float* x  = (const float*)d_in[0];
  const float* Wr = (const float*)d_in[1];
  const float* W1 = (const float*)d_in[2];
  const float* b1 = (const float*)d_in[3];
  const float* W2 = (const float*)d_in[4];
  const float* b2 = (const float*)d_in[5];
  float* y = (float*)d_out;
  float* aux = y + (size_t)out_size - 1;

  char* ws = (char*)d_ws;
  float* probs    = (float*)ws; ws += (size_t)NTOK * NE * 4;   // 512 KB
  float* C0       = (float*)ws; ws += 32 * NE * 4;
  float* C1       = (float*)ws; ws += 32 * NE * 4;
  int*   eidx     = (int*)ws;   ws += NTOK * 2 * 4;
  float* ew       = (float*)ws; ws += NTOK * 2 * 4;
  int*   slot_tok = (int*)ws;   ws += NE * CAP * 4;
  int*   tok2slot = (int*)ws;   ws += NTOK * 2 * 4;
  int*   counts   = (int*)ws;   ws += 256;
  int*   cnt      = (int*)ws;   ws += NCHUNK * NE * 4;
  int*   cbase    = (int*)ws;   ws += NCHUNK * NE * 4;
  _Float16* xg    = (_Float16*)ws; ws += (size_t)NE * CAP * DM * 2;   // 20 MB
  _Float16* hbuf  = (_Float16*)ws; ws += (size_t)NE * CAP * HD * 2;   // 80 MB
  _Float16* P1b   = (_Float16*)ws; ws += (size_t)NE * CAP * DM * 2;   // 20 MB
  _Float16* P0b   = xg;   // xg dead after k_gemm1

  hipMemsetAsync(slot_tok, 0xFF, (size_t)NE * CAP * 4, stream);

  k_router<<<NTOK / 4, 256, 0, stream>>>(x, Wr, probs, C0);
  k_sink<<<32, 256, 0, stream>>>(probs, C0, C1);
  k_sink<<<32, 256, 0, stream>>>(probs, C1, C0);
  k_sink3<<<32, 256, 0, stream>>>(probs, C0, eidx, ew, cnt);
  k_prefix<<<1, 64, 0, stream>>>(cnt, cbase, counts, aux);
  k_assign<<<NCHUNK, 256, 0, stream>>>(eidx, cbase, slot_tok, tok2slot);
  k_gather<<<NE * CAP, 256, 0, stream>>>(x, slot_tok, xg);

  k_gemm1<<<2560, 256, 0, stream>>>(xg, W1, b1, hbuf);
  k_gemm2<<<1280, 256, 0, stream>>>(hbuf, W2, b2, P0b, P1b);

  k_combine<<<NTOK, 256, 0, stream>>>(P0b, P1b, tok2slot, ew, y);
}

// Round 16
// 383.109 us; speedup vs baseline: 1.0931x; 1.0001x over previous
//
#include <hip/hip_runtime.h>
#include <hip/hip_bf16.h>
#include <math.h>

#define NTOK 8192
#define DM   1024
#define NE   16
#define HD   4096
#define CAP  640
#define NCHUNK 64   // (NTOK*2)/256

typedef float f32x4 __attribute__((ext_vector_type(4)));
typedef _Float16 f16x8 __attribute__((ext_vector_type(8)));
typedef _Float16 f16x4 __attribute__((ext_vector_type(4)));

__device__ __forceinline__ void gload16(const void* g, void* l) {
  __builtin_amdgcn_global_load_lds(
      (const __attribute__((address_space(1))) unsigned int*)g,
      (__attribute__((address_space(3))) unsigned int*)l, 16, 0, 0);
}

// fast GELU (tanh form)
__device__ __forceinline__ float gelu_fast(float v) {
  float v2 = v * v;
  float z2n = v * fmaf(-0.07135481627f, v2, -1.595769122f);
  float e = __expf(z2n);
  return v / (1.0f + e);
}

// ---------------- router: logits + softmax + col partials (one wave/token) ----------------
__global__ __launch_bounds__(256) void k_router(const float* __restrict__ x,
                                                const float* __restrict__ Wr,
                                                float* __restrict__ probs,
                                                float* __restrict__ pout) {
  int wave = threadIdx.x >> 6, lane = threadIdx.x & 63;
  int tok = blockIdx.x * 4 + wave;
  const float* xr = x + (size_t)tok * DM;
  float acc[NE];
#pragma unroll
  for (int e = 0; e < NE; ++e) acc[e] = 0.f;
  for (int d = lane; d < DM; d += 64) {
    float xv = xr[d];
    const float* w = Wr + (size_t)d * NE;
#pragma unroll
    for (int e = 0; e < NE; ++e) acc[e] = fmaf(xv, w[e], acc[e]);
  }
#pragma unroll
  for (int off = 32; off >= 1; off >>= 1) {
#pragma unroll
    for (int e = 0; e < NE; ++e) acc[e] += __shfl_xor(acc[e], off, 64);
  }
  float m = acc[0];
#pragma unroll
  for (int e = 1; e < NE; ++e) m = fmaxf(m, acc[e]);
  float s = 0.f;
#pragma unroll
  for (int e = 0; e < NE; ++e) { acc[e] = expf(acc[e] - m); s += acc[e]; }
  float inv = 1.0f / s;
#pragma unroll
  for (int e = 0; e < NE; ++e) acc[e] *= inv;
  if (lane < NE) probs[(size_t)tok * NE + lane] = acc[lane];
  __shared__ float wsum[4][NE];
  if (lane == 0) {
#pragma unroll
    for (int e = 0; e < NE; ++e) wsum[wave][e] = acc[e];
  }
  __syncthreads();
  if (threadIdx.x < NE)
    pout[blockIdx.x * NE + threadIdx.x] =
        wsum[0][threadIdx.x] + wsum[1][threadIdx.x] + wsum[2][threadIdx.x] + wsum[3][threadIdx.x];
}

// ------------- fused sinkhorn step -------------
__global__ __launch_bounds__(256) void k_sink(float* __restrict__ probs,
                                              const float* __restrict__ pin,
                                              float* __restrict__ pout) {
  __shared__ float csinv[NE];
  int tid = threadIdx.x;
  if (tid < NE) {
    float s = 0.f;
#pragma unroll
    for (int b = 0; b < 32; ++b) s += pin[b * NE + tid];
    csinv[tid] = 512.0f / s;
  }
  __syncthreads();
  int tok = blockIdx.x * 256 + tid;
  float* row = probs + (size_t)tok * NE;
  float p[NE]; float rs = 0.f;
#pragma unroll
  for (int e = 0; e < NE; ++e) { p[e] = row[e] * csinv[e]; rs += p[e]; }
  float rinv = 1.0f / rs;
#pragma unroll
  for (int e = 0; e < NE; ++e) { p[e] *= rinv; row[e] = p[e]; }
#pragma unroll
  for (int off = 32; off >= 1; off >>= 1) {
#pragma unroll
    for (int e = 0; e < NE; ++e) p[e] += __shfl_xor(p[e], off, 64);
  }
  __shared__ float wsum[4][NE];
  int lane = tid & 63, wave = tid >> 6;
  if (lane == 0) {
#pragma unroll
    for (int e = 0; e < NE; ++e) wsum[wave][e] = p[e];
  }
  __syncthreads();
  if (tid < NE)
    pout[blockIdx.x * NE + tid] =
        wsum[0][tid] + wsum[1][tid] + wsum[2][tid] + wsum[3][tid];
}

// ------------- final col-normalize + top-2 + renorm + fused per-chunk histogram -------------
// Block b handles tokens b*256..b*256+255 = dispatch entries 512b..512b+511 = chunks 2b, 2b+1.
__global__ __launch_bounds__(256) void k_sink3(const float* __restrict__ probs,
                                               const float* __restrict__ pin,
                                               int* __restrict__ eidx,
                                               float* __restrict__ ew,
                                               int* __restrict__ cnt) {
  __shared__ float csinv[NE];
  __shared__ int h0[NE], h1[NE];
  int tid = threadIdx.x;
  if (tid < NE) {
    float s = 0.f;
#pragma unroll
    for (int b = 0; b < 32; ++b) s += pin[b * NE + tid];
    csinv[tid] = 512.0f / s;
    h0[tid] = 0; h1[tid] = 0;
  }
  __syncthreads();
  int tok = blockIdx.x * 256 + tid;
  const float* row = probs + (size_t)tok * NE;
  float v0 = -1e30f, v1 = -1e30f; int e0 = 0, e1 = 0;
#pragma unroll
  for (int e = 0; e < NE; ++e) {
    float v = row[e] * csinv[e];
    if (v > v0) { v1 = v0; e1 = e0; v0 = v; e0 = e; }
    else if (v > v1) { v1 = v; e1 = e; }
  }
  float s = v0 + v1;
  eidx[tok * 2] = e0; eidx[tok * 2 + 1] = e1;
  ew[tok * 2] = v0 / s; ew[tok * 2 + 1] = v1 / s;
  // entries 2*tok, 2*tok+1 belong to chunk 2b (tid<128) or 2b+1 (tid>=128)
  int* hh = (tid < 128) ? h0 : h1;
  atomicAdd(&hh[e0], 1);
  atomicAdd(&hh[e1], 1);
  __syncthreads();
  if (tid < NE) cnt[(2 * blockIdx.x) * NE + tid] = h0[tid];
  else if (tid >= 32 && tid < 32 + NE) cnt[(2 * blockIdx.x + 1) * NE + (tid - 32)] = h1[tid - 32];
}

// ------------- per-expert exclusive prefix over chunks + aux loss -------------
__global__ __launch_bounds__(64) void k_prefix(const int* __restrict__ cnt,
                                               int* __restrict__ base,
                                               int* __restrict__ counts,
                                               float* __restrict__ aux) {
  __shared__ int tot[NE];
  int e = threadIdx.x;
  if (e < NE) {
    int run = 0;
    for (int c = 0; c < NCHUNK; ++c) {
      base[c * NE + e] = run;
      run += cnt[c * NE + e];
    }
    counts[e] = run;
    tot[e] = min(run, CAP);
  }
  __syncthreads();
  if (e == 0) {
    int s = 0;
#pragma unroll
    for (int i = 0; i < NE; ++i) s += tot[i];
    *aux = 0.01f * (float)s / (float)NTOK;
  }
}

__global__ __launch_bounds__(256) void k_assign(const int* __restrict__ eidx,
                                                const int* __restrict__ base,
                                                int* __restrict__ slot_tok,
                                                int* __restrict__ tok2slot) {
  __shared__ int wcnt[4][NE];
  __shared__ int cbase[NE];
  int tid = threadIdx.x, c = blockIdx.x, lane = tid & 63, wave = tid >> 6;
  int i = c * 256 + tid;
  int myE = eidx[i];
  if (tid < NE) cbase[tid] = base[c * NE + tid];
  int mypre = 0;
#pragma unroll
  for (int e = 0; e < NE; ++e) {
    unsigned long long m = __ballot(myE == e);
    if (myE == e) mypre = __popcll(m & ((1ull << lane) - 1ull));
    if (lane == 0) wcnt[wave][e] = __popcll(m);
  }
  __syncthreads();
  int pre = 0;
  for (int w = 0; w < wave; ++w) pre += wcnt[w][myE];
  int pos = cbase[myE] + pre + mypre;
  if (pos < CAP) {
    slot_tok[myE * CAP + pos] = i >> 1;
    tok2slot[i] = myE * CAP + pos;
  } else {
    tok2slot[i] = -1;
  }
}

// ------------- gather expert inputs to fp16 (zero-fill unused slots) -------------
__global__ __launch_bounds__(256) void k_gather(const float* __restrict__ x,
                                                const int* __restrict__ slot_tok,
                                                _Float16* __restrict__ xg) {
  int row = blockIdx.x;
  int tok = slot_tok[row];
  int t = threadIdx.x;
  f16x4 h;
  if (tok >= 0) {
    float4 v = *(const float4*)(x + (size_t)tok * DM + t * 4);
    h[0] = (_Float16)v.x; h[1] = (_Float16)v.y; h[2] = (_Float16)v.z; h[3] = (_Float16)v.w;
  } else {
    h[0] = (_Float16)0.f; h[1] = (_Float16)0.f; h[2] = (_Float16)0.f; h[3] = (_Float16)0.f;
  }
  *(f16x4*)(xg + (size_t)row * DM + t * 4) = h;
}

// ==================== fp16 MFMA GEMMs, async A-dbuf + counted vmcnt (r9-proven) ====================
// A-LDS: double-buffered [128][64k] fp16 (16 KB each), 16B chunks XOR-swizzled (c ^= row&7),
//        filled by global_load_lds (pre-swizzled global source, linear LDS dest).
// B-LDS: [128n][64k] fp16, chunk pos = kc ^ ((n^(n>>2))&7), reg-staged from fp32 W (fused
//        transpose+convert). B prefetch (8 float4) issued one k-step early.
// Loop: raw s_barrier + counted vmcnt(8) at step end (A(t+1)'s 4 gload16 drained, 8 B-loads
//       stay in flight) — A staging latency hides under the MFMA phase.

__device__ __forceinline__ void stage_tileA128(const _Float16* gbase, int ld, int k0,
                                               _Float16* lds, int w, int lane) {
#pragma unroll
  for (int i = 0; i < 4; ++i) {
    int ci = (w * 4 + i) * 64 + lane;
    int row = ci >> 3, c = ci & 7;
    int cs = c ^ (row & 7);
    gload16(gbase + (size_t)row * ld + k0 + cs * 8, lds + (w * 4 + i) * 512);
  }
}

__device__ __forceinline__ void loadB8(const float* gb, int ld, int k0, int tid, float4* L) {
  int nq = tid & 31, kc = tid >> 5;
  const float* p = gb + (size_t)(k0 + kc * 8) * ld + nq * 4;
#pragma unroll
  for (int j = 0; j < 8; ++j) L[j] = *(const float4*)(p + (size_t)j * ld);
}

__device__ __forceinline__ void writeB(_Float16* Bs, int tid, const float4* L) {
  int nq = tid & 31, kc = tid >> 5;
#pragma unroll
  for (int i = 0; i < 4; ++i) {
    int n = nq * 4 + i;
    int pos = kc ^ ((n ^ (n >> 2)) & 7);
    f16x8 v;
#pragma unroll
    for (int j = 0; j < 8; ++j) {
      float f = (i == 0) ? L[j].x : (i == 1) ? L[j].y : (i == 2) ? L[j].z : L[j].w;
      v[j] = (_Float16)f;
    }
    *(f16x8*)(Bs + n * 64 + pos * 8) = v;
  }
}

#define MFMA_PHASE(Ac, Bs)                                                         \
  _Pragma("unroll")                                                                \
  for (int ks = 0; ks < 2; ++ks) {                                                 \
    f16x8 af[4], bf[4];                                                            \
    _Pragma("unroll")                                                              \
    for (int m = 0; m < 4; ++m) {                                                  \
      int row = wr * 64 + m * 16 + lr;                                             \
      int cs = (ks * 4 + kg) ^ (row & 7);                                          \
      af[m] = *(const f16x8*)((Ac) + row * 64 + cs * 8);                           \
    }                                                                              \
    _Pragma("unroll")                                                              \
    for (int n = 0; n < 4; ++n) {                                                  \
      int row = wc * 64 + n * 16 + lr;                                             \
      int cs = (ks * 4 + kg) ^ ((row ^ (row >> 2)) & 7);                           \
      bf[n] = *(const f16x8*)((Bs) + row * 64 + cs * 8);                           \
    }                                                                              \
    __builtin_amdgcn_s_setprio(1);                                                 \
    _Pragma("unroll")                                                              \
    for (int m = 0; m < 4; ++m)                                                    \
      _Pragma("unroll")                                                            \
      for (int n = 0; n < 4; ++n)                                                  \
        acc[m][n] = __builtin_amdgcn_mfma_f32_16x16x32_f16(af[m], bf[n], acc[m][n], 0, 0, 0); \
    __builtin_amdgcn_s_setprio(0);                                                 \
  }

#define ASYNC_K_LOOP(NT, AB, ALD, BB, BLD, KBASE)                                  \
  {                                                                                \
    stage_tileA128((AB), (ALD), (KBASE), As0, w, lane);                            \
    loadB8((BB), (BLD), (KBASE), tid, L);                                          \
    asm volatile("s_waitcnt vmcnt(0)" ::: "memory");                               \
    __builtin_amdgcn_s_barrier();                                                  \
    __builtin_amdgcn_sched_barrier(0);                                             \
    for (int t = 0; t < (NT); ++t) {                                               \
      const _Float16* Ac = (t & 1) ? As1 : As0;                                    \
      _Float16* An = (t & 1) ? As0 : As1;                                          \
      writeB(Bs, tid, L);                                                          \
      if (t + 1 < (NT)) {                                                          \
        stage_tileA128((AB), (ALD), (KBASE) + (t + 1) * 64, An, w, lane);          \
        loadB8((BB), (BLD), (KBASE) + (t + 1) * 64, tid, L);                       \
      }                                                                            \
      asm volatile("s_waitcnt lgkmcnt(0)" ::: "memory");                           \
      __builtin_amdgcn_s_barrier();                                                \
      __builtin_amdgcn_sched_barrier(0);                                           \
      MFMA_PHASE(Ac, Bs);                                                          \
      __builtin_amdgcn_sched_barrier(0);                                           \
      if (t + 1 < (NT)) { asm volatile("s_waitcnt vmcnt(8)" ::: "memory"); }       \
      else              { asm volatile("s_waitcnt vmcnt(0)" ::: "memory"); }       \
      __builtin_amdgcn_s_barrier();                                                \
      __builtin_amdgcn_sched_barrier(0);                                           \
    }                                                                              \
  }

// ---- GEMM1: h = gelu(xg @ W1 + b1), 128x128 tile, 2560 blocks ----
__global__ __launch_bounds__(256) void k_gemm1(const _Float16* __restrict__ xg,
                                               const float* __restrict__ W1,
                                               const float* __restrict__ b1,
                                               _Float16* __restrict__ hbuf) {
  __shared__ _Float16 smem[3 * 128 * 64];     // As0 | As1 | Bs ; first 32 KB reused as bounce
  _Float16* As0 = smem;
  _Float16* As1 = smem + 8192;
  _Float16* Bs  = smem + 16384;
  int bid = blockIdx.x;
  int logical = (bid & 7) * 320 + (bid >> 3);
  int my = logical % 5;
  int nx = (logical / 5) % 32;
  int e  = logical / 160;
  int m0 = my * 128, n0 = nx * 128;
  const _Float16* Ab = xg + ((size_t)e * CAP + m0) * DM;
  const float*    Bb = W1 + (size_t)e * DM * HD + n0;     // ld = HD
  int tid = threadIdx.x, lane = tid & 63, w = tid >> 6;
  int wr = w >> 1, wc = w & 1;
  int lr = lane & 15, kg = lane >> 4;

  f32x4 acc[4][4];
#pragma unroll
  for (int m = 0; m < 4; ++m)
#pragma unroll
    for (int n = 0; n < 4; ++n) acc[m][n] = (f32x4){0.f, 0.f, 0.f, 0.f};

  float4 L[8];
  ASYNC_K_LOOP(16, Ab, DM, Bb, HD, 0);

  // epilogue: bias + fast GELU -> fp16, bounce via LDS for coalesced stores
  __syncthreads();
  _Float16* Cb = smem;
  int lq = lane >> 4;
#pragma unroll
  for (int n = 0; n < 4; ++n) {
    int col = wc * 64 + n * 16 + lr;
    float bias = b1[(size_t)e * HD + n0 + col];
#pragma unroll
    for (int m = 0; m < 4; ++m) {
#pragma unroll
      for (int r = 0; r < 4; ++r) {
        int row = wr * 64 + m * 16 + lq * 4 + r;
        float v = gelu_fast(acc[m][n][r] + bias);
        Cb[row * 128 + (col ^ (((row >> 2) & 3) << 4))] = (_Float16)v;
      }
    }
  }
  __syncthreads();
  int rr = tid >> 4;
  int c8 = (tid & 15) * 8;
#pragma unroll
  for (int p = 0; p < 8; ++p) {
    int row = p * 16 + rr;
    int colx = c8 ^ (((row >> 2) & 3) << 4);
    f16x8 v = *(const f16x8*)(Cb + row * 128 + colx);
    *(f16x8*)(hbuf + ((size_t)e * CAP + m0 + row) * HD + n0 + c8) = v;
  }
}

// ---- GEMM2: Pks[e][slot] = h @ W2[kslice] (+b2 on ks==0), 128x128 tile, K-split 2, 1280 blocks ----
__global__ __launch_bounds__(256) void k_gemm2(const _Float16* __restrict__ hbuf,
                                               const float* __restrict__ W2,
                                               const float* __restrict__ b2,
                                               _Float16* __restrict__ P0,
                                               _Float16* __restrict__ P1) {
  __shared__ _Float16 smem[3 * 128 * 64];
  _Float16* As0 = smem;
  _Float16* As1 = smem + 8192;
  _Float16* Bs  = smem + 16384;
  int bid = blockIdx.x;
  int logical = (bid & 7) * 160 + (bid >> 3);
  int my = logical % 5;
  int nx = (logical / 5) % 8;
  int ks2 = (logical / 40) & 1;
  int e  = logical / 80;
  int m0 = my * 128, n0 = nx * 128, kbase = ks2 * 2048;
  const _Float16* Ab = hbuf + ((size_t)e * CAP + m0) * HD;
  const float*    Bb = W2 + (size_t)e * HD * DM + n0;     // ld = DM
  int tid = threadIdx.x, lane = tid & 63, w = tid >> 6;
  int wr = w >> 1, wc = w & 1;
  int lr = lane & 15, kg = lane >> 4;

  f32x4 acc[4][4];
#pragma unroll
  for (int m = 0; m < 4; ++m)
#pragma unroll
    for (int n = 0; n < 4; ++n) acc[m][n] = (f32x4){0.f, 0.f, 0.f, 0.f};

  float4 L[8];
  ASYNC_K_LOOP(32, Ab, HD, Bb, DM, kbase);

  // epilogue: (+bias on ks==0) -> fp16 partial via LDS bounce
  __syncthreads();
  _Float16* Cb = smem;
  _Float16* P = (ks2 == 0) ? P0 : P1;
  int lq = lane >> 4;
  float bias[4];
#pragma unroll
  for (int n = 0; n < 4; ++n)
    bias[n] = (ks2 == 0) ? b2[(size_t)e * DM + n0 + wc * 64 + n * 16 + lr] : 0.f;
#pragma unroll
  for (int m = 0; m < 4; ++m) {
#pragma unroll
    for (int n = 0; n < 4; ++n) {
#pragma unroll
      for (int r = 0; r < 4; ++r) {
        int row = wr * 64 + m * 16 + lq * 4 + r;
        int col = wc * 64 + n * 16 + lr;
        Cb[row * 128 + (col ^ (((row >> 2) & 3) << 4))] = (_Float16)(acc[m][n][r] + bias[n]);
      }
    }
  }
  __syncthreads();
  int rr = tid >> 4;
  int c8 = (tid & 15) * 8;
#pragma unroll
  for (int p = 0; p < 8; ++p) {
    int row = p * 16 + rr;
    int colx = c8 ^ (((row >> 2) & 3) << 4);
    f16x8 v = *(const f16x8*)(Cb + row * 128 + colx);
    *(f16x8*)(P + ((size_t)e * CAP + m0 + row) * DM + n0 + c8) = v;
  }
}

// ---- combine: y[t] = sum_k w_k * (P0[slot]+P1[slot]) ----
__global__ __launch_bounds__(256) void k_combine(const _Float16* __restrict__ P0,
                                                 const _Float16* __restrict__ P1,
                                                 const int* __restrict__ tok2slot,
                                                 const float* __restrict__ ew,
                                                 float* __restrict__ y) {
  int t = blockIdx.x;
  int d = threadIdx.x * 4;
  int i0 = tok2slot[t * 2], i1 = tok2slot[t * 2 + 1];
  float w0 = ew[t * 2], w1 = ew[t * 2 + 1];
  float a0 = 0.f, a1 = 0.f, a2 = 0.f, a3 = 0.f;
  if (i0 >= 0) {
    f16x4 oa = *(const f16x4*)(P0 + (size_t)i0 * DM + d);
    f16x4 ob = *(const f16x4*)(P1 + (size_t)i0 * DM + d);
    a0 += w0 * ((float)oa[0] + (float)ob[0]); a1 += w0 * ((float)oa[1] + (float)ob[1]);
    a2 += w0 * ((float)oa[2] + (float)ob[2]); a3 += w0 * ((float)oa[3] + (float)ob[3]);
  }
  if (i1 >= 0) {
    f16x4 oa = *(const f16x4*)(P0 + (size_t)i1 * DM + d);
    f16x4 ob = *(const f16x4*)(P1 + (size_t)i1 * DM + d);
    a0 += w1 * ((float)oa[0] + (float)ob[0]); a1 += w1 * ((float)oa[1] + (float)ob[1]);
    a2 += w1 * ((float)oa[2] + (float)ob[2]); a3 += w1 * ((float)oa[3] + (float)ob[3]);
  }
  float4 out = make_float4(a0, a1, a2, a3);
  *(float4*)(y + (size_t)t * DM + d) = out;
}

extern "C" void kernel_launch(void* const* d_in, const int* in_sizes, int n_in,
                              void* d_out, int out_size, void* d_ws, size_t ws_size,
                              hipStream_t stream) {
  const float* x  = (const float*)d_in[0];
  const float* Wr = (const float*)d_in[1];
  const float* W1 = (const float*)d_in[2];
  const float* b1 = (const float*)d_in[3];
  const float* W2 = (const float*)d_in[4];
  const float* b2 = (const float*)d_in[5];
  float* y = (float*)d_out;
  float* aux = y + (size_t)out_size - 1;

  char* ws = (char*)d_ws;
  float* probs    = (float*)ws; ws += (size_t)NTOK * NE * 4;   // 512 KB
  float* C0       = (float*)ws; ws += 32 * NE * 4;
  float* C1       = (float*)ws; ws += 32 * NE * 4;
  int*   eidx     = (int*)ws;   ws += NTOK * 2 * 4;
  float* ew       = (float*)ws; ws += NTOK * 2 * 4;
  int*   slot_tok = (int*)ws;   ws += NE * CAP * 4;
  int*   tok2slot = (int*)ws;   ws += NTOK * 2 * 4;
  int*   counts   = (int*)ws;   ws += 256;
  int*   cnt      = (int*)ws;   ws += NCHUNK * NE * 4;
  int*   cbase    = (int*)ws;   ws += NCHUNK * NE * 4;
  _Float16* xg    = (_Float16*)ws; ws += (size_t)NE * CAP * DM * 2;   // 20 MB
  _Float16* hbuf  = (_Float16*)ws; ws += (size_t)NE * CAP * HD * 2;   // 80 MB
  _Float16* P1b   = (_Float16*)ws; ws += (size_t)NE * CAP * DM * 2;   // 20 MB
  _Float16* P0b   = xg;   // xg dead after k_gemm1

  hipMemsetAsync(slot_tok, 0xFF, (size_t)NE * CAP * 4, stream);

  k_router<<<NTOK / 4, 256, 0, stream>>>(x, Wr, probs, C0);
  k_sink<<<32, 256, 0, stream>>>(probs, C0, C1);
  k_sink<<<32, 256, 0, stream>>>(probs, C1, C0);
  k_sink3<<<32, 256, 0, stream>>>(probs, C0, eidx, ew, cnt);
  k_prefix<<<1, 64, 0, stream>>>(cnt, cbase, counts, aux);
  k_assign<<<NCHUNK, 256, 0, stream>>>(eidx, cbase, slot_tok, tok2slot);
  k_gather<<<NE * CAP, 256, 0, stream>>>(x, slot_tok, xg);

  k_gemm1<<<2560, 256, 0, stream>>>(xg, W1, b1, hbuf);
  k_gemm2<<<1280, 256, 0, stream>>>(hbuf, W2, b2, P0b, P1b);

  k_combine<<<NTOK, 256, 0, stream>>>(P0b, P1b, tok2slot, ew, y);
}

// Round 18
// 381.375 us; speedup vs baseline: 1.0981x; 1.0045x over previous
//
#include <hip/hip_runtime.h>
#include <hip/hip_bf16.h>
#include <math.h>

#define NTOK 8192
#define DM   1024
#define NE   16
#define HD   4096
#define CAP  640
#define NCHUNK 64   // (NTOK*2)/256

typedef float f32x4 __attribute__((ext_vector_type(4)));
typedef _Float16 f16x8 __attribute__((ext_vector_type(8)));
typedef _Float16 f16x4 __attribute__((ext_vector_type(4)));
typedef __fp16 fp16v2 __attribute__((ext_vector_type(2)));   // native type of cvt_pkrtz

__device__ __forceinline__ void gload16(const void* g, void* l) {
  __builtin_amdgcn_global_load_lds(
      (const __attribute__((address_space(1))) unsigned int*)g,
      (__attribute__((address_space(3))) unsigned int*)l, 16, 0, 0);
}

// fast GELU (tanh form)
__device__ __forceinline__ float gelu_fast(float v) {
  float v2 = v * v;
  float z2n = v * fmaf(-0.07135481627f, v2, -1.595769122f);
  float e = __expf(z2n);
  return v / (1.0f + e);
}

// ---------------- router: logits + softmax + col partials (one wave/token) ----------------
__global__ __launch_bounds__(256) void k_router(const float* __restrict__ x,
                                                const float* __restrict__ Wr,
                                                float* __restrict__ probs,
                                                float* __restrict__ pout) {
  int wave = threadIdx.x >> 6, lane = threadIdx.x & 63;
  int tok = blockIdx.x * 4 + wave;
  const float* xr = x + (size_t)tok * DM;
  float acc[NE];
#pragma unroll
  for (int e = 0; e < NE; ++e) acc[e] = 0.f;
  for (int d = lane; d < DM; d += 64) {
    float xv = xr[d];
    const float* w = Wr + (size_t)d * NE;
#pragma unroll
    for (int e = 0; e < NE; ++e) acc[e] = fmaf(xv, w[e], acc[e]);
  }
#pragma unroll
  for (int off = 32; off >= 1; off >>= 1) {
#pragma unroll
    for (int e = 0; e < NE; ++e) acc[e] += __shfl_xor(acc[e], off, 64);
  }
  float m = acc[0];
#pragma unroll
  for (int e = 1; e < NE; ++e) m = fmaxf(m, acc[e]);
  float s = 0.f;
#pragma unroll
  for (int e = 0; e < NE; ++e) { acc[e] = expf(acc[e] - m); s += acc[e]; }
  float inv = 1.0f / s;
#pragma unroll
  for (int e = 0; e < NE; ++e) acc[e] *= inv;
  if (lane < NE) probs[(size_t)tok * NE + lane] = acc[lane];
  __shared__ float wsum[4][NE];
  if (lane == 0) {
#pragma unroll
    for (int e = 0; e < NE; ++e) wsum[wave][e] = acc[e];
  }
  __syncthreads();
  if (threadIdx.x < NE)
    pout[blockIdx.x * NE + threadIdx.x] =
        wsum[0][threadIdx.x] + wsum[1][threadIdx.x] + wsum[2][threadIdx.x] + wsum[3][threadIdx.x];
}

// ------------- fused sinkhorn step -------------
__global__ __launch_bounds__(256) void k_sink(float* __restrict__ probs,
                                              const float* __restrict__ pin,
                                              float* __restrict__ pout) {
  __shared__ float csinv[NE];
  int tid = threadIdx.x;
  if (tid < NE) {
    float s = 0.f;
#pragma unroll
    for (int b = 0; b < 32; ++b) s += pin[b * NE + tid];
    csinv[tid] = 512.0f / s;
  }
  __syncthreads();
  int tok = blockIdx.x * 256 + tid;
  float* row = probs + (size_t)tok * NE;
  float p[NE]; float rs = 0.f;
#pragma unroll
  for (int e = 0; e < NE; ++e) { p[e] = row[e] * csinv[e]; rs += p[e]; }
  float rinv = 1.0f / rs;
#pragma unroll
  for (int e = 0; e < NE; ++e) { p[e] *= rinv; row[e] = p[e]; }
#pragma unroll
  for (int off = 32; off >= 1; off >>= 1) {
#pragma unroll
    for (int e = 0; e < NE; ++e) p[e] += __shfl_xor(p[e], off, 64);
  }
  __shared__ float wsum[4][NE];
  int lane = tid & 63, wave = tid >> 6;
  if (lane == 0) {
#pragma unroll
    for (int e = 0; e < NE; ++e) wsum[wave][e] = p[e];
  }
  __syncthreads();
  if (tid < NE)
    pout[blockIdx.x * NE + tid] =
        wsum[0][tid] + wsum[1][tid] + wsum[2][tid] + wsum[3][tid];
}

// ------------- final col-normalize + top-2 + renorm + fused per-chunk histogram -------------
__global__ __launch_bounds__(256) void k_sink3(const float* __restrict__ probs,
                                               const float* __restrict__ pin,
                                               int* __restrict__ eidx,
                                               float* __restrict__ ew,
                                               int* __restrict__ cnt) {
  __shared__ float csinv[NE];
  __shared__ int h0[NE], h1[NE];
  int tid = threadIdx.x;
  if (tid < NE) {
    float s = 0.f;
#pragma unroll
    for (int b = 0; b < 32; ++b) s += pin[b * NE + tid];
    csinv[tid] = 512.0f / s;
    h0[tid] = 0; h1[tid] = 0;
  }
  __syncthreads();
  int tok = blockIdx.x * 256 + tid;
  const float* row = probs + (size_t)tok * NE;
  float v0 = -1e30f, v1 = -1e30f; int e0 = 0, e1 = 0;
#pragma unroll
  for (int e = 0; e < NE; ++e) {
    float v = row[e] * csinv[e];
    if (v > v0) { v1 = v0; e1 = e0; v0 = v; e0 = e; }
    else if (v > v1) { v1 = v; e1 = e; }
  }
  float s = v0 + v1;
  eidx[tok * 2] = e0; eidx[tok * 2 + 1] = e1;
  ew[tok * 2] = v0 / s; ew[tok * 2 + 1] = v1 / s;
  int* hh = (tid < 128) ? h0 : h1;
  atomicAdd(&hh[e0], 1);
  atomicAdd(&hh[e1], 1);
  __syncthreads();
  if (tid < NE) cnt[(2 * blockIdx.x) * NE + tid] = h0[tid];
  else if (tid >= 32 && tid < 32 + NE) cnt[(2 * blockIdx.x + 1) * NE + (tid - 32)] = h1[tid - 32];
}

// ------------- per-expert exclusive prefix over chunks + aux loss -------------
__global__ __launch_bounds__(64) void k_prefix(const int* __restrict__ cnt,
                                               int* __restrict__ base,
                                               int* __restrict__ counts,
                                               float* __restrict__ aux) {
  __shared__ int tot[NE];
  int e = threadIdx.x;
  if (e < NE) {
    int run = 0;
    for (int c = 0; c < NCHUNK; ++c) {
      base[c * NE + e] = run;
      run += cnt[c * NE + e];
    }
    counts[e] = run;
    tot[e] = min(run, CAP);
  }
  __syncthreads();
  if (e == 0) {
    int s = 0;
#pragma unroll
    for (int i = 0; i < NE; ++i) s += tot[i];
    *aux = 0.01f * (float)s / (float)NTOK;
  }
}

__global__ __launch_bounds__(256) void k_assign(const int* __restrict__ eidx,
                                                const int* __restrict__ base,
                                                int* __restrict__ slot_tok,
                                                int* __restrict__ tok2slot) {
  __shared__ int wcnt[4][NE];
  __shared__ int cbase[NE];
  int tid = threadIdx.x, c = blockIdx.x, lane = tid & 63, wave = tid >> 6;
  int i = c * 256 + tid;
  int myE = eidx[i];
  if (tid < NE) cbase[tid] = base[c * NE + tid];
  int mypre = 0;
#pragma unroll
  for (int e = 0; e < NE; ++e) {
    unsigned long long m = __ballot(myE == e);
    if (myE == e) mypre = __popcll(m & ((1ull << lane) - 1ull));
    if (lane == 0) wcnt[wave][e] = __popcll(m);
  }
  __syncthreads();
  int pre = 0;
  for (int w = 0; w < wave; ++w) pre += wcnt[w][myE];
  int pos = cbase[myE] + pre + mypre;
  if (pos < CAP) {
    slot_tok[myE * CAP + pos] = i >> 1;
    tok2slot[i] = myE * CAP + pos;
  } else {
    tok2slot[i] = -1;
  }
}

// ------------- gather expert inputs to fp16 (zero-fill unused slots) -------------
__global__ __launch_bounds__(256) void k_gather(const float* __restrict__ x,
                                                const int* __restrict__ slot_tok,
                                                _Float16* __restrict__ xg) {
  int row = blockIdx.x;
  int tok = slot_tok[row];
  int t = threadIdx.x;
  f16x4 h;
  if (tok >= 0) {
    float4 v = *(const float4*)(x + (size_t)tok * DM + t * 4);
    h[0] = (_Float16)v.x; h[1] = (_Float16)v.y; h[2] = (_Float16)v.z; h[3] = (_Float16)v.w;
  } else {
    h[0] = (_Float16)0.f; h[1] = (_Float16)0.f; h[2] = (_Float16)0.f; h[3] = (_Float16)0.f;
  }
  *(f16x4*)(xg + (size_t)row * DM + t * 4) = h;
}

// ==================== fp16 MFMA GEMMs, async A-dbuf + counted vmcnt (r9-proven) ====================
// A-LDS: double-buffered [128][64k] fp16 (16 KB each), 16B chunks XOR-swizzled (c ^= row&7),
//        filled by global_load_lds (pre-swizzled global source, linear LDS dest).
// B-LDS: [128n][64k] fp16, chunk pos = kc ^ ((n^(n>>2))&7), reg-staged from fp32 W (fused
//        transpose+convert with PACKED v_cvt_pkrtz, 16 instrs vs 32 scalar cvts).
// Loop: raw s_barrier + counted vmcnt(8) at step end (A(t+1)'s 4 gload16 drained, 8 B-loads
//       stay in flight) — A staging latency hides under the MFMA phase.

__device__ __forceinline__ void stage_tileA128(const _Float16* gbase, int ld, int k0,
                                               _Float16* lds, int w, int lane) {
#pragma unroll
  for (int i = 0; i < 4; ++i) {
    int ci = (w * 4 + i) * 64 + lane;
    int row = ci >> 3, c = ci & 7;
    int cs = c ^ (row & 7);
    gload16(gbase + (size_t)row * ld + k0 + cs * 8, lds + (w * 4 + i) * 512);
  }
}

__device__ __forceinline__ void loadB8(const float* gb, int ld, int k0, int tid, float4* L) {
  int nq = tid & 31, kc = tid >> 5;
  const float* p = gb + (size_t)(k0 + kc * 8) * ld + nq * 4;
#pragma unroll
  for (int j = 0; j < 8; ++j) L[j] = *(const float4*)(p + (size_t)j * ld);
}

__device__ __forceinline__ float fcomp(const float4& f, int i) {
  return (i == 0) ? f.x : (i == 1) ? f.y : (i == 2) ? f.z : f.w;
}

__device__ __forceinline__ void writeB(_Float16* Bs, int tid, const float4* L) {
  int nq = tid & 31, kc = tid >> 5;
#pragma unroll
  for (int i = 0; i < 4; ++i) {
    int n = nq * 4 + i;
    int pos = kc ^ ((n ^ (n >> 2)) & 7);
    union { fp16v2 h2[4]; f16x8 v; } u;
#pragma unroll
    for (int j = 0; j < 4; ++j)
      u.h2[j] = __builtin_amdgcn_cvt_pkrtz(fcomp(L[2 * j], i), fcomp(L[2 * j + 1], i));
    *(f16x8*)(Bs + n * 64 + pos * 8) = u.v;
  }
}

#define MFMA_PHASE(Ac, Bs)                                                         \
  _Pragma("unroll")                                                                \
  for (int ks = 0; ks < 2; ++ks) {                                                 \
    f16x8 af[4], bf[4];                                                            \
    _Pragma("unroll")                                                              \
    for (int m = 0; m < 4; ++m) {                                                  \
      int row = wr * 64 + m * 16 + lr;                                             \
      int cs = (ks * 4 + kg) ^ (row & 7);                                          \
      af[m] = *(const f16x8*)((Ac) + row * 64 + cs * 8);                           \
    }                                                                              \
    _Pragma("unroll")                                                              \
    for (int n = 0; n < 4; ++n) {                                                  \
      int row = wc * 64 + n * 16 + lr;                                             \
      int cs = (ks * 4 + kg) ^ ((row ^ (row >> 2)) & 7);                           \
      bf[n] = *(const f16x8*)((Bs) + row * 64 + cs * 8);                           \
    }                                                                              \
    __builtin_amdgcn_s_setprio(1);                                                 \
    _Pragma("unroll")                                                              \
    for (int m = 0; m < 4; ++m)                                                    \
      _Pragma("unroll")                                                            \
      for (int n = 0; n < 4; ++n)                                                  \
        acc[m][n] = __builtin_amdgcn_mfma_f32_16x16x32_f16(af[m], bf[n], acc[m][n], 0, 0, 0); \
    __builtin_amdgcn_s_setprio(0);                                                 \
  }

#define ASYNC_K_LOOP(NT, AB, ALD, BB, BLD, KBASE)                                  \
  {                                                                                \
    stage_tileA128((AB), (ALD), (KBASE), As0, w, lane);                            \
    loadB8((BB), (BLD), (KBASE), tid, L);                                          \
    asm volatile("s_waitcnt vmcnt(0)" ::: "memory");                               \
    __builtin_amdgcn_s_barrier();                                                  \
    __builtin_amdgcn_sched_barrier(0);                                             \
    for (int t = 0; t < (NT); ++t) {                                               \
      const _Float16* Ac = (t & 1) ? As1 : As0;                                    \
      _Float16* An = (t & 1) ? As0 : As1;                                          \
      writeB(Bs, tid, L);                                                          \
      if (t + 1 < (NT)) {                                                          \
        stage_tileA128((AB), (ALD), (KBASE) + (t + 1) * 64, An, w, lane);          \
        loadB8((BB), (BLD), (KBASE) + (t + 1) * 64, tid, L);                       \
      }                                                                            \
      asm volatile("s_waitcnt lgkmcnt(0)" ::: "memory");                           \
      __builtin_amdgcn_s_barrier();                                                \
      __builtin_amdgcn_sched_barrier(0);                                           \
      MFMA_PHASE(Ac, Bs);                                                          \
      __builtin_amdgcn_sched_barrier(0);                                           \
      if (t + 1 < (NT)) { asm volatile("s_waitcnt vmcnt(8)" ::: "memory"); }       \
      else              { asm volatile("s_waitcnt vmcnt(0)" ::: "memory"); }       \
      __builtin_amdgcn_s_barrier();                                                \
      __builtin_amdgcn_sched_barrier(0);                                           \
    }                                                                              \
  }

// ---- GEMM1: h = gelu(xg @ W1 + b1), 128x128 tile, 2560 blocks ----
__global__ __launch_bounds__(256) void k_gemm1(const _Float16* __restrict__ xg,
                                               const float* __restrict__ W1,
                                               const float* __restrict__ b1,
                                               _Float16* __restrict__ hbuf) {
  __shared__ _Float16 smem[3 * 128 * 64];     // As0 | As1 | Bs ; first 32 KB reused as bounce
  _Float16* As0 = smem;
  _Float16* As1 = smem + 8192;
  _Float16* Bs  = smem + 16384;
  int bid = blockIdx.x;
  int logical = (bid & 7) * 320 + (bid >> 3);
  int my = logical % 5;
  int nx = (logical / 5) % 32;
  int e  = logical / 160;
  int m0 = my * 128, n0 = nx * 128;
  const _Float16* Ab = xg + ((size_t)e * CAP + m0) * DM;
  const float*    Bb = W1 + (size_t)e * DM * HD + n0;     // ld = HD
  int tid = threadIdx.x, lane = tid & 63, w = tid >> 6;
  int wr = w >> 1, wc = w & 1;
  int lr = lane & 15, kg = lane >> 4;

  f32x4 acc[4][4];
#pragma unroll
  for (int m = 0; m < 4; ++m)
#pragma unroll
    for (int n = 0; n < 4; ++n) acc[m][n] = (f32x4){0.f, 0.f, 0.f, 0.f};

  float4 L[8];
  ASYNC_K_LOOP(16, Ab, DM, Bb, HD, 0);

  // epilogue: bias + fast GELU -> fp16, bounce via LDS for coalesced stores
  __syncthreads();
  _Float16* Cb = smem;
  int lq = lane >> 4;
#pragma unroll
  for (int n = 0; n < 4; ++n) {
    int col = wc * 64 + n * 16 + lr;
    float bias = b1[(size_t)e * HD + n0 + col];
#pragma unroll
    for (int m = 0; m < 4; ++m) {
#pragma unroll
      for (int r = 0; r < 4; ++r) {
        int row = wr * 64 + m * 16 + lq * 4 + r;
        float v = gelu_fast(acc[m][n][r] + bias);
        Cb[row * 128 + (col ^ (((row >> 2) & 3) << 4))] = (_Float16)v;
      }
    }
  }
  __syncthreads();
  int rr = tid >> 4;
  int c8 = (tid & 15) * 8;
#pragma unroll
  for (int p = 0; p < 8; ++p) {
    int row = p * 16 + rr;
    int colx = c8 ^ (((row >> 2) & 3) << 4);
    f16x8 v = *(const f16x8*)(Cb + row * 128 + colx);
    *(f16x8*)(hbuf + ((size_t)e * CAP + m0 + row) * HD + n0 + c8) = v;
  }
}

// ---- GEMM2: Pks[e][slot] = h @ W2[kslice] (+b2 on ks==0), 128x128 tile, K-split 2, 1280 blocks ----
__global__ __launch_bounds__(256) void k_gemm2(const _Float16* __restrict__ hbuf,
                                               const float* __restrict__ W2,
                                               const float* __restrict__ b2,
                                               _Float16* __restrict__ P0,
                                               _Float16* __restrict__ P1) {
  __shared__ _Float16 smem[3 * 128 * 64];
  _Float16* As0 = smem;
  _Float16* As1 = smem + 8192;
  _Float16* Bs  = smem + 16384;
  int bid = blockIdx.x;
  int logical = (bid & 7) * 160 + (bid >> 3);
  int my = logical % 5;
  int nx = (logical / 5) % 8;
  int ks2 = (logical / 40) & 1;
  int e  = logical / 80;
  int m0 = my * 128, n0 = nx * 128, kbase = ks2 * 2048;
  const _Float16* Ab = hbuf + ((size_t)e * CAP + m0) * HD;
  const float*    Bb = W2 + (size_t)e * HD * DM + n0;     // ld = DM
  int tid = threadIdx.x, lane = tid & 63, w = tid >> 6;
  int wr = w >> 1, wc = w & 1;
  int lr = lane & 15, kg = lane >> 4;

  f32x4 acc[4][4];
#pragma unroll
  for (int m = 0; m < 4; ++m)
#pragma unroll
    for (int n = 0; n < 4; ++n) acc[m][n] = (f32x4){0.f, 0.f, 0.f, 0.f};

  float4 L[8];
  ASYNC_K_LOOP(32, Ab, HD, Bb, DM, kbase);

  // epilogue: (+bias on ks==0) -> fp16 partial via LDS bounce
  __syncthreads();
  _Float16* Cb = smem;
  _Float16* P = (ks2 == 0) ? P0 : P1;
  int lq = lane >> 4;
  float bias[4];
#pragma unroll
  for (int n = 0; n < 4; ++n)
    bias[n] = (ks2 == 0) ? b2[(size_t)e * DM + n0 + wc * 64 + n * 16 + lr] : 0.f;
#pragma unroll
  for (int m = 0; m < 4; ++m) {
#pragma unroll
    for (int n = 0; n < 4; ++n) {
#pragma unroll
      for (int r = 0; r < 4; ++r) {
        int row = wr * 64 + m * 16 + lq * 4 + r;
        int col = wc * 64 + n * 16 + lr;
        Cb[row * 128 + (col ^ (((row >> 2) & 3) << 4))] = (_Float16)(acc[m][n][r] + bias[n]);
      }
    }
  }
  __syncthreads();
  int rr = tid >> 4;
  int c8 = (tid & 15) * 8;
#pragma unroll
  for (int p = 0; p < 8; ++p) {
    int row = p * 16 + rr;
    int colx = c8 ^ (((row >> 2) & 3) << 4);
    f16x8 v = *(const f16x8*)(Cb + row * 128 + colx);
    *(f16x8*)(P + ((size_t)e * CAP + m0 + row) * DM + n0 + c8) = v;
  }
}

// ---- combine: y[t] = sum_k w_k * (P0[slot]+P1[slot]) ----
__global__ __launch_bounds__(256) void k_combine(const _Float16* __restrict__ P0,
                                                 const _Float16* __restrict__ P1,
                                                 const int* __restrict__ tok2slot,
                                                 const float* __restrict__ ew,
                                                 float* __restrict__ y) {
  int t = blockIdx.x;
  int d = threadIdx.x * 4;
  int i0 = tok2slot[t * 2], i1 = tok2slot[t * 2 + 1];
  float w0 = ew[t * 2], w1 = ew[t * 2 + 1];
  float a0 = 0.f, a1 = 0.f, a2 = 0.f, a3 = 0.f;
  if (i0 >= 0) {
    f16x4 oa = *(const f16x4*)(P0 + (size_t)i0 * DM + d);
    f16x4 ob = *(const f16x4*)(P1 + (size_t)i0 * DM + d);
    a0 += w0 * ((float)oa[0] + (float)ob[0]); a1 += w0 * ((float)oa[1] + (float)ob[1]);
    a2 += w0 * ((float)oa[2] + (float)ob[2]); a3 += w0 * ((float)oa[3] + (float)ob[3]);
  }
  if (i1 >= 0) {
    f16x4 oa = *(const f16x4*)(P0 + (size_t)i1 * DM + d);
    f16x4 ob = *(const f16x4*)(P1 + (size_t)i1 * DM + d);
    a0 += w1 * ((float)oa[0] + (float)ob[0]); a1 += w1 * ((float)oa[1] + (float)ob[1]);
    a2 += w1 * ((float)oa[2] + (float)ob[2]); a3 += w1 * ((float)oa[3] + (float)ob[3]);
  }
  float4 out = make_float4(a0, a1, a2, a3);
  *(float4*)(y + (size_t)t * DM + d) = out;
}

extern "C" void kernel_launch(void* const* d_in, const int* in_sizes, int n_in,
                              void* d_out, int out_size, void* d_ws, size_t ws_size,
                              hipStream_t stream) {
  const float* x  = (const float*)d_in[0];
  const float* Wr = (const float*)d_in[1];
  const float* W1 = (const float*)d_in[2];
  const float* b1 = (const float*)d_in[3];
  const float* W2 = (const float*)d_in[4];
  const float* b2 = (const float*)d_in[5];
  float* y = (float*)d_out;
  float* aux = y + (size_t)out_size - 1;

  char* ws = (char*)d_ws;
  float* probs    = (float*)ws; ws += (size_t)NTOK * NE * 4;   // 512 KB
  float* C0       = (float*)ws; ws += 32 * NE * 4;
  float* C1       = (float*)ws; ws += 32 * NE * 4;
  int*   eidx     = (int*)ws;   ws += NTOK * 2 * 4;
  float* ew       = (float*)ws; ws += NTOK * 2 * 4;
  int*   slot_tok = (int*)ws;   ws += NE * CAP * 4;
  int*   tok2slot = (int*)ws;   ws += NTOK * 2 * 4;
  int*   counts   = (int*)ws;   ws += 256;
  int*   cnt      = (int*)ws;   ws += NCHUNK * NE * 4;
  int*   cbase    = (int*)ws;   ws += NCHUNK * NE * 4;
  _Float16* xg    = (_Float16*)ws; ws += (size_t)NE * CAP * DM * 2;   // 20 MB
  _Float16* hbuf  = (_Float16*)ws; ws += (size_t)NE * CAP * HD * 2;   // 80 MB
  _Float16* P1b   = (_Float16*)ws; ws += (size_t)NE * CAP * DM * 2;   // 20 MB
  _Float16* P0b   = xg;   // xg dead after k_gemm1

  (void)hipMemsetAsync(slot_tok, 0xFF, (size_t)NE * CAP * 4, stream);

  k_router<<<NTOK / 4, 256, 0, stream>>>(x, Wr, probs, C0);
  k_sink<<<32, 256, 0, stream>>>(probs, C0, C1);
  k_sink<<<32, 256, 0, stream>>>(probs, C1, C0);
  k_sink3<<<32, 256, 0, stream>>>(probs, C0, eidx, ew, cnt);
  k_prefix<<<1, 64, 0, stream>>>(cnt, cbase, counts, aux);
  k_assign<<<NCHUNK, 256, 0, stream>>>(eidx, cbase, slot_tok, tok2slot);
  k_gather<<<NE * CAP, 256, 0, stream>>>(x, slot_tok, xg);

  k_gemm1<<<2560, 256, 0, stream>>>(xg, W1, b1, hbuf);
  k_gemm2<<<1280, 256, 0, stream>>>(hbuf, W2, b2, P0b, P1b);

  k_combine<<<NTOK, 256, 0, stream>>>(P0b, P1b, tok2slot, ew, y);
}